// Round 1
// 1771.742 us; speedup vs baseline: 1.0500x; 1.0500x over previous
//
#include <hip/hip_runtime.h>
#include <math.h>

// Model dims: H=512 D=128 L=8 T=64 W=240 CTX=60 NSTEPS=30

typedef __attribute__((ext_vector_type(8))) short short8;
typedef __attribute__((ext_vector_type(4))) float floatx4;
typedef unsigned long long ull;

__device__ __forceinline__ float sigf(float x) { return 1.f / (1.f + __expf(-x)); }
__device__ __forceinline__ float tanh_f(float x) {
    float e = __expf(2.f * x);
    return 1.f - 2.f / (e + 1.f);
}
__device__ __forceinline__ unsigned short f2b(float x) {   // fp32 -> bf16 RNE
    unsigned u = __float_as_uint(x);
    unsigned r = (u + 0x7FFFu + ((u >> 16) & 1u)) >> 16;
    return (unsigned short)r;
}

// RELAXED agent-scope atomics only (acquire/release emit buffer_inv/wbl2 on
// gfx950 and trash the XCD L2 — R4->R5 lesson). Cross-block payloads are
// published as ONE 8-byte word {epoch|data}: consumer polls the word itself,
// so data+readiness arrive in a single MALL round-trip (vs flag RT + data RT).
// R7: polls are BATCHED — all of a thread's epoch-words are loaded as
// independent loads in one loop body so their MALL latencies overlap (the old
// per-word waitfe chain serialized 2-5 round trips per hop). Re-reading an
// already-matched word is safe: every slot's next-epoch write is gated on this
// consumer passing (applied->obuf->h chain / pyr parity chain), so a matched
// word cannot change under the poll loop.
__device__ __forceinline__ float gld(const float* p) {
    return __hip_atomic_load(p, __ATOMIC_RELAXED, __HIP_MEMORY_SCOPE_AGENT);
}
__device__ __forceinline__ void gst(float* p, float v) {
    __hip_atomic_store(p, v, __ATOMIC_RELAXED, __HIP_MEMORY_SCOPE_AGENT);
}
__device__ __forceinline__ ull gldll(const ull* p) {
    return __hip_atomic_load(p, __ATOMIC_RELAXED, __HIP_MEMORY_SCOPE_AGENT);
}
__device__ __forceinline__ void gstll(ull* p, ull v) {
    __hip_atomic_store(p, v, __ATOMIC_RELAXED, __HIP_MEMORY_SCOPE_AGENT);
}
__device__ __forceinline__ ull packfe(float d, int ep) {
    return ((ull)(unsigned)ep << 32) | (ull)__float_as_uint(d);
}
__device__ __forceinline__ float lowf(ull v) { return __uint_as_float((unsigned)v); }
__device__ __forceinline__ void set_flag(int* f, int v) {
    __hip_atomic_store(f, v, __ATOMIC_RELAXED, __HIP_MEMORY_SCOPE_AGENT);
}
__device__ __forceinline__ void wait_flag_ge(int* f, int ep) {
    while (__hip_atomic_load(f, __ATOMIC_RELAXED, __HIP_MEMORY_SCOPE_AGENT) < ep)
        __builtin_amdgcn_s_sleep(1);
}

// ---------------------------------------------------------------------------
// init: zero [hbufF | flagsE | hp1 | hp2 | hdec_p | app_p | obuf_p] = 142864 f
// ---------------------------------------------------------------------------
__global__ void init_k(float* __restrict__ ws) {
    for (int i = blockIdx.x * blockDim.x + threadIdx.x; i < 142864; i += gridDim.x * blockDim.x)
        ws[i] = 0.f;
}

// ---------------------------------------------------------------------------
// Encoder, ONE persistent launch, 64 steps, bf16 MFMA (unchanged from R6).
// ---------------------------------------------------------------------------
__global__ void __launch_bounds__(256, 1) enc_all(
    const float* __restrict__ data,
    const float* __restrict__ Wih, const float* __restrict__ Whh,
    const float* __restrict__ bih, const float* __restrict__ bhh,
    ull* __restrict__ hbufF,        // [2][15][16][64] x (2 ull)
    float* __restrict__ henc,       // [240][512] fp32 final h
    int* __restrict__ flags)        // [240][32]
{
    __shared__ short act2[20 * 64 * 8];
    __shared__ float gw[4][640];
    __shared__ float cs[512];
    __shared__ short hw[4][16][8];
    __shared__ float biasL[4][4][8];

    const int tid = threadIdx.x;
    const int fg = blockIdx.x >> 4, ds = blockIdx.x & 15;
    const int w = tid >> 6, lane = tid & 63;
    const int n = lane & 15, q = lane >> 4;

    short8 bfrag[2][20];
#pragma unroll
    for (int nt = 0; nt < 2; ++nt) {
        int rr = nt * 16 + n;
        int g = rr >> 3, dp = rr & 7;
        int grow = g * 512 + ds * 32 + w * 8 + dp;
#pragma unroll
        for (int kt = 0; kt < 20; ++kt) {
            int k0 = kt * 32 + q * 8;
            const float* src = (k0 < 512) ? (Whh + (size_t)grow * 512 + k0)
                                          : (Wih + (size_t)grow * 128 + (k0 - 512));
            float4 lo = *(const float4*)src;
            float4 hi = *(const float4*)(src + 4);
            short8 bf;
            bf[0] = (short)f2b(lo.x); bf[1] = (short)f2b(lo.y);
            bf[2] = (short)f2b(lo.z); bf[3] = (short)f2b(lo.w);
            bf[4] = (short)f2b(hi.x); bf[5] = (short)f2b(hi.y);
            bf[6] = (short)f2b(hi.z); bf[7] = (short)f2b(hi.w);
            bfrag[nt][kt] = bf;
        }
    }
    if (tid < 128) {
        int w2 = tid >> 5, rr = tid & 31;
        int g = rr >> 3, dp = rr & 7;
        int grow = g * 512 + ds * 32 + w2 * 8 + dp;
        biasL[w2][g][dp] = bih[grow] + bhh[grow];
    }
    for (int i = tid; i < 512; i += 256) cs[i] = 0.f;
    __syncthreads();

    ull* a2ll = (ull*)act2;

    for (int t = 0; t < 64; ++t) {
        if (t > 0) {
            if (tid < 16) wait_flag_ge(&flags[(fg * 16 + tid) * 32], t);
        }
        __syncthreads();

        {
            const ull* hsrc = hbufF + (size_t)(((t & 1) * 15 + fg) * 16) * 64 * 2;
            for (int i = tid; i < 2048; i += 256) a2ll[i] = gldll(hsrc + i);
            int kt2 = tid >> 6, l2 = tid & 63, f2 = l2 & 15, q2 = l2 >> 4;
            const float* xs = data + ((size_t)t * 240 + fg * 16 + f2) * 128 + kt2 * 32 + q2 * 8;
            float4 lo = *(const float4*)xs;
            float4 hi = *(const float4*)(xs + 4);
            short8 xp;
            xp[0] = (short)f2b(lo.x); xp[1] = (short)f2b(lo.y);
            xp[2] = (short)f2b(lo.z); xp[3] = (short)f2b(lo.w);
            xp[4] = (short)f2b(hi.x); xp[5] = (short)f2b(hi.y);
            xp[6] = (short)f2b(hi.z); xp[7] = (short)f2b(hi.w);
            *(short8*)&act2[((16 + kt2) * 64 + l2) * 8] = xp;
        }
        __syncthreads();

        floatx4 acc0 = {0.f, 0.f, 0.f, 0.f};
        floatx4 acc1 = {0.f, 0.f, 0.f, 0.f};
#pragma unroll
        for (int kt = 0; kt < 20; ++kt) {
            short8 a = *(short8*)&act2[(kt * 64 + lane) * 8];
            acc0 = __builtin_amdgcn_mfma_f32_16x16x32_bf16(a, bfrag[0][kt], acc0, 0, 0, 0);
            acc1 = __builtin_amdgcn_mfma_f32_16x16x32_bf16(a, bfrag[1][kt], acc1, 0, 0, 0);
        }
        *(floatx4*)&gw[w][(0 * 16 + n) * 20 + 4 * q] = acc0;
        *(floatx4*)&gw[w][(1 * 16 + n) * 20 + 4 * q] = acc1;

        int nb = (t + 1) & 1;
#pragma unroll
        for (int it = 0; it < 2; ++it) {
            int f = lane & 15, dp = q + 4 * it;
            float gi = gw[w][(0 * 8 + dp) * 20 + f] + biasL[w][0][dp];
            float gf = gw[w][(1 * 8 + dp) * 20 + f] + biasL[w][1][dp];
            float gg = gw[w][(2 * 8 + dp) * 20 + f] + biasL[w][2][dp];
            float go = gw[w][(3 * 8 + dp) * 20 + f] + biasL[w][3][dp];
            int ci = f * 32 + w * 8 + dp;
            float cc = cs[ci];
            float cn = sigf(gf) * cc + sigf(gi) * tanh_f(gg);
            float hn = sigf(go) * tanh_f(cn);
            cs[ci] = cn;
            hw[w][f][dp] = (short)f2b(hn);
            if (t == 63)
                gst(&henc[(size_t)(fg * 16 + f) * 512 + ds * 32 + w * 8 + dp], hn);
        }
        if (lane < 16) {
            const ull* hwp = (const ull*)&hw[w][lane][0];
            ull* dst = hbufF + (size_t)((((nb * 15 + fg) * 16 + ds) * 64) + w * 16 + lane) * 2;
            gstll(dst + 0, hwp[0]); gstll(dst + 1, hwp[1]);
        }
        __syncthreads();
        if (tid == 0) set_flag(&flags[(fg * 16 + ds) * 32], t + 1);
    }
}

// ---------------------------------------------------------------------------
// xp GEMM (unchanged)
// ---------------------------------------------------------------------------
__global__ void __launch_bounds__(256) gemm_xp(
    const float* __restrict__ A, int M, int K, int rev,
    const float* __restrict__ Wv, const float* __restrict__ ba, const float* __restrict__ bb,
    float* __restrict__ C)
{
    __shared__ float At[16][66];
    __shared__ float Wt[128][66];
    const int tid = threadIdx.x;
    const int nt = blockIdx.x & 15, mt = blockIdx.x >> 4;
    const int rp = tid >> 2, fq = tid & 3;
    const int lr0 = 2 * rp, lr1 = lr0 + 1;
    const int n0 = nt * 128 + lr0, n1 = n0 + 1;

    float acc0[4], acc1[4];
    {
        float b0 = ba[n0] + bb[n0], b1 = ba[n1] + bb[n1];
#pragma unroll
        for (int j = 0; j < 4; ++j) { acc0[j] = b0; acc1[j] = b1; }
    }

    for (int kt = 0; kt < K; kt += 64) {
        {
            int f = tid >> 4, c4 = tid & 15;
            int m = mt * 16 + f;
            float4 v = make_float4(0.f, 0.f, 0.f, 0.f);
            if (m < M) {
                int ar = rev ? (M - 1 - m) : m;
                v = ((const float4*)(A + (size_t)ar * K + kt))[c4];
            }
            At[f][c4 * 4 + 0] = v.x; At[f][c4 * 4 + 1] = v.y;
            At[f][c4 * 4 + 2] = v.z; At[f][c4 * 4 + 3] = v.w;
        }
        for (int i = tid; i < 2048; i += 256) {
            int lr = i >> 4, c4 = i & 15;
            float4 v = ((const float4*)(Wv + (size_t)(nt * 128 + lr) * K + kt))[c4];
            Wt[lr][c4 * 4 + 0] = v.x; Wt[lr][c4 * 4 + 1] = v.y;
            Wt[lr][c4 * 4 + 2] = v.z; Wt[lr][c4 * 4 + 3] = v.w;
        }
        __syncthreads();
        const float2* w0p = (const float2*)(&Wt[lr0][0]);
        const float2* w1p = (const float2*)(&Wt[lr1][0]);
#pragma unroll 8
        for (int kh = 0; kh < 32; ++kh) {
            float2 w0 = w0p[kh], w1 = w1p[kh];
#pragma unroll
            for (int j = 0; j < 4; ++j) {
                float2 av = ((const float2*)(&At[4 * fq + j][0]))[kh];
                acc0[j] += w0.x * av.x + w0.y * av.y;
                acc1[j] += w1.x * av.x + w1.y * av.y;
            }
        }
        __syncthreads();
    }
#pragma unroll
    for (int j = 0; j < 4; ++j) {
        int m = mt * 16 + 4 * fq + j;
        if (m < M) {
            C[(size_t)m * 2048 + n0] = acc0[j];
            C[(size_t)m * 2048 + n1] = acc1[j];
        }
    }
}

// ---------------------------------------------------------------------------
// Pyramidal bi-LSTM. grid 128 = dir(2) x blk(64); 8 dims/block.
// h exchanged as {epoch|float} ull words, parity double-buffered:
// hp[dir][parity][512]. R7: the per-step h gather is batch-polled (2 words
// issued together) — one overlapped MALL window instead of 2 serial ones.
// ---------------------------------------------------------------------------
__global__ void __launch_bounds__(256, 1) pyr_rec(
    const float* __restrict__ xpF, const float* __restrict__ xpB,
    const float* __restrict__ WhhF, const float* __restrict__ WhhB,
    ull* __restrict__ hp,      // [dir][2][512]
    float* __restrict__ outF, float* __restrict__ outB,
    int steps)
{
    const int tid = threadIdx.x;
    const int dir = blockIdx.x >> 6, blk = blockIdx.x & 63;
    const float* xp  = dir ? xpB : xpF;
    const float* Whh = dir ? WhhB : WhhF;
    float* outp = dir ? outB : outF;
    ull* hpd = hp + (size_t)dir * 1024;

    __shared__ __align__(16) float hcur[512];
    __shared__ float red[32][9];
    __shared__ float gv[32];

    const int lr = tid & 31, seg = tid >> 5;
    const int grow = (lr >> 3) * 512 + blk * 8 + (lr & 7);
    float4 wl4[16];
#pragma unroll
    for (int j = 0; j < 16; ++j)
        wl4[j] = *(const float4*)&Whh[(size_t)grow * 512 + 4 * seg + 32 * j];

    const int growx = (tid >> 3) * 512 + blk * 8 + (tid & 7);   // for tid<32
    float creg = 0.f;
    __syncthreads();

    for (int t = 0; t < steps; ++t) {
        float xg = 0.f;
        if (tid < 32) xg = xp[(size_t)t * 2048 + growx];   // prefetch (no h dep)
        {
            const ull* base = hpd + (size_t)(t & 1) * 512;
            ull v0, v1;
            do {
                v0 = gldll(base + tid);
                v1 = gldll(base + tid + 256);
            } while (((int)(v0 >> 32) != t) | ((int)(v1 >> 32) != t));
            hcur[tid]       = lowf(v0);
            hcur[tid + 256] = lowf(v1);
        }
        __syncthreads();

        float a = 0.f;
#pragma unroll
        for (int j = 0; j < 16; ++j) {
            float4 w = wl4[j];
            float4 h4 = *(const float4*)&hcur[4 * seg + 32 * j];
            a += w.x*h4.x + w.y*h4.y + w.z*h4.z + w.w*h4.w;
        }
        red[lr][seg] = a;
        __syncthreads();

        if (tid < 32) {
            float g = xg;
#pragma unroll
            for (int s2 = 0; s2 < 8; ++s2) g += red[tid][s2];
            gv[tid] = g;
        }
        __syncthreads();
        if (tid < 8) {
            float i_ = sigf(gv[tid]), f_ = sigf(gv[8 + tid]);
            float g_ = tanh_f(gv[16 + tid]), o_ = sigf(gv[24 + tid]);
            creg = f_ * creg + i_ * g_;
            float hn = o_ * tanh_f(creg);
            int d = blk * 8 + tid;
            gstll(&hpd[((t + 1) & 1) * 512 + d], packfe(hn, t + 1));
            int row = dir ? (steps - 1 - t) : t;
            outp[(size_t)row * 512 + d] = hn;
        }
        __syncthreads();
    }
}

__global__ void x2_assemble(const float* __restrict__ f1, const float* __restrict__ b1o,
                            float* __restrict__ x2)
{
    int j = blockIdx.x;
    for (int k = threadIdx.x; k < 2048; k += 256) {
        int q = k >> 9, r = k & 511;
        const float* src = (q & 1) ? b1o : f1;
        int row = 2 * j + (q >> 1);
        x2[(size_t)j * 2048 + k] = src[(size_t)row * 512 + r];
    }
}

// ctx assemble + publish hdec chunks with epoch 0
__global__ void ctx_k(const float* __restrict__ f2, const float* __restrict__ b2o,
                      float* __restrict__ ctx, ull* __restrict__ hdec_p)
{
    int j = blockIdx.x;
    for (int k = threadIdx.x; k < 1024; k += 256)
        ctx[(size_t)j * 1024 + k] = (k < 512) ? f2[(size_t)j * 512 + k]
                                              : b2o[(size_t)j * 512 + k - 512];
    if (j == 0) {
        for (int i = threadIdx.x; i < 512; i += 256)
            hdec_p[i] = packfe(f2[59 * 512 + i], 0);
    }
}

// ---------------------------------------------------------------------------
// Decoder: 66 blocks, 1 block/CU, register weights (float4 mod-N interleave).
// All cross-block payloads are {epoch|data} ull words, single-slot (safety
// proven via the applied->obuf->h gating chain). 3 one-RT hops per step.
// R7: (a) each hop's per-thread poll words are loaded in ONE batched window
// (h: 2, applied: 5, o: 2 -> 9 serial RTs/step collapse to 3); (b) both
// softmaxes (60-wide attn, 8-wide logits) are shuffle-parallel instead of
// tid==0 serial loops.
// ---------------------------------------------------------------------------
__global__ void __launch_bounds__(256, 1) dec_k(
    const float* __restrict__ attn_W, const float* __restrict__ attn_b,
    const float* __restrict__ comb_W, const float* __restrict__ comb_b,
    const float* __restrict__ gWih, const float* __restrict__ gWhh,
    const float* __restrict__ gbih, const float* __restrict__ gbhh,
    const float* __restrict__ outW, const float* __restrict__ outb,
    const float* __restrict__ ctx,
    ull* __restrict__ hdec_p,   // [512]
    ull* __restrict__ app_p,    // [1032] = inp(8) + applied(1024)
    ull* __restrict__ obuf_p,   // [512]
    float* __restrict__ dout)
{
    const int tid = threadIdx.x, bid = blockIdx.x;
    __shared__ float ctxL[60 * 516];                 // attn role
    __shared__ __align__(16) float hx[528];          // [inpl(8); h(512); pad0(8)]
    __shared__ __align__(16) float xl[1160];         // [inp(8); applied(1024); pad0]
    __shared__ float redA[64][5];
    __shared__ float redG[32][9];
    __shared__ float redC[8][33];
    __shared__ float redO[8][33];
    __shared__ float ghl[24], gil[24];
    __shared__ float aw[60];
    __shared__ float biasg[24], biasi[24], biasc[8];

    const bool attn_role = (bid < 2);
    const int gbid = bid - 2;
    const int dbase = gbid * 8;

    float4 wa4[33]; float4 wo4[4];          // attn role
    float4 wg4[16], wi4[16], wc4[9];        // gru role
    const int rz = tid >> 2, sz = tid & 3;  // z: rows(60/64), 4 segs
    const int ro = tid >> 5, so = tid & 31; // logits: 8 rows, 32 segs
    const int rg = tid >> 3, sg = tid & 7;  // gh/gi: rows(24/32), 8 segs
    const int rc = tid >> 5, sc = tid & 31; // comb: 8 rows, 32 segs

    if (attn_role) {
        int rr = (rz < 60) ? rz : 59;
#pragma unroll
        for (int i = 0; i < 32; ++i)
            wa4[i] = *(const float4*)&attn_W[(size_t)rr * 520 + 4 * sz + 16 * i];
        {
            float* wap = (float*)&wa4[32];
#pragma unroll
            for (int r = 0; r < 4; ++r) {
                int k = 4 * sz + 512 + r;
                wap[r] = (k < 520) ? attn_W[(size_t)rr * 520 + k] : 0.f;
            }
        }
#pragma unroll
        for (int i = 0; i < 4; ++i)
            wo4[i] = *(const float4*)&outW[(size_t)ro * 512 + 4 * so + 128 * i];
        for (int i = tid; i < 7680; i += 256) {
            int j = i >> 7, c4 = i & 127;
            float4 v = ((const float4*)(ctx + (size_t)j * 1024 + bid * 512))[c4];
            *(float4*)&ctxL[j * 516 + c4 * 4] = v;
        }
        if (tid < 8) hx[520 + tid] = 0.f;
    } else {
        int rr = (rg < 24) ? rg : 23;
        int grow = (rr >> 3) * 512 + dbase + (rr & 7);
#pragma unroll
        for (int j = 0; j < 16; ++j) {
            wg4[j] = *(const float4*)&gWhh[(size_t)grow * 512 + 4 * sg + 32 * j];
            wi4[j] = *(const float4*)&gWih[(size_t)grow * 512 + 4 * sg + 32 * j];
        }
#pragma unroll
        for (int i = 0; i < 8; ++i)
            wc4[i] = *(const float4*)&comb_W[(size_t)(dbase + rc) * 1032 + 4 * sc + 128 * i];
        {
            float* wcp = (float*)&wc4[8];
#pragma unroll
            for (int r = 0; r < 4; ++r) {
                int k = 4 * sc + 1024 + r;
                wcp[r] = (k < 1032) ? comb_W[(size_t)(dbase + rc) * 1032 + k] : 0.f;
            }
        }
        if (tid < 24) {
            int g2 = (tid >> 3) * 512 + dbase + (tid & 7);
            biasg[tid] = gbhh[g2];
            biasi[tid] = gbih[g2];
        }
        if (tid < 8) biasc[tid] = comb_b[dbase + tid];
        for (int i = tid; i < 128; i += 256) xl[1032 + i] = 0.f;
    }
    __syncthreads();

    for (int s = 0; s < 30; ++s) {
        // ---- hop 1: h (epoch s), batched poll: 2 words/thread in one window ----
        {
            ull v0, v1;
            do {
                v0 = gldll(&hdec_p[tid]);
                v1 = gldll(&hdec_p[tid + 256]);
            } while (((int)(v0 >> 32) != s) | ((int)(v1 >> 32) != s));
            hx[8 + tid]       = lowf(v0);
            hx[8 + tid + 256] = lowf(v1);
        }
        __syncthreads();

        if (attn_role) {
            if (s > 0) {   // logits of previous step
                {
                    float a = 0.f;
#pragma unroll
                    for (int i = 0; i < 4; ++i) {
                        float4 w = wo4[i];
                        float4 h4 = *(const float4*)&hx[8 + 4 * so + 128 * i];
                        a += w.x*h4.x + w.y*h4.y + w.z*h4.z + w.w*h4.w;
                    }
                    redO[ro][so] = a;
                }
                __syncthreads();
                if (tid < 8) {   // shuffle-parallel 8-wide log-softmax (lanes 0..7)
                    float a = outb[tid];
#pragma unroll
                    for (int g2 = 0; g2 < 32; ++g2) a += redO[tid][g2];
                    float m = a;
                    m = fmaxf(m, __shfl_xor(m, 1));
                    m = fmaxf(m, __shfl_xor(m, 2));
                    m = fmaxf(m, __shfl_xor(m, 4));
                    float e = __expf(a - m);
                    float ss = e;
                    ss += __shfl_xor(ss, 1);
                    ss += __shfl_xor(ss, 2);
                    ss += __shfl_xor(ss, 4);
                    float lp = a - m - __logf(ss);
                    hx[tid] = lp;
                    if (bid == 0) {
                        dout[(s - 1) * 8 + tid] = lp;
                        gstll(&app_p[tid], packfe(lp, s + 1));
                    }
                }
            } else {
                if (tid < 8) {
                    float v = (tid == 7) ? 1.f : 0.f;
                    hx[tid] = v;
                    if (bid == 0) gstll(&app_p[tid], packfe(v, 1));
                }
            }
            __syncthreads();
            {   // z = attn_W @ [inp; h] ; k = 4sz + 16i + r over hx[0..520)
                float a = 0.f;
#pragma unroll
                for (int i = 0; i < 33; ++i) {
                    float4 w = wa4[i];
                    float4 x4 = *(const float4*)&hx[4 * sz + 16 * i];
                    a += w.x*x4.x + w.y*x4.y + w.z*x4.z + w.w*x4.w;
                }
                redA[rz][sz] = a;
            }
            __syncthreads();
            if (tid < 64) {   // wave-0 parallel 60-wide softmax
                float z = -1e30f;
                if (tid < 60)
                    z = attn_b[tid] + redA[tid][0] + redA[tid][1] + redA[tid][2] + redA[tid][3];
                float m = z;
#pragma unroll
                for (int off = 32; off; off >>= 1) m = fmaxf(m, __shfl_xor(m, off));
                float e = (tid < 60) ? __expf(z - m) : 0.f;
                float ss = e;
#pragma unroll
                for (int off = 32; off; off >>= 1) ss += __shfl_xor(ss, off);
                if (tid < 60) aw[tid] = e / ss;
            }
            __syncthreads();
            for (int cc = tid; cc < 512; cc += 256) {
                float a = 0.f;
                for (int j = 0; j < 60; ++j) a += aw[j] * ctxL[j * 516 + cc];
                gstll(&app_p[8 + bid * 512 + cc], packfe(a, s + 1));
            }
            __syncthreads();
        } else {
            {   // gh = gWhh @ h ; k = 4sg + 32j + r (broadcast LDS reads)
                float a = 0.f;
#pragma unroll
                for (int j = 0; j < 16; ++j) {
                    float4 w = wg4[j];
                    float4 h4 = *(const float4*)&hx[8 + 4 * sg + 32 * j];
                    a += w.x*h4.x + w.y*h4.y + w.z*h4.z + w.w*h4.w;
                }
                redG[rg][sg] = a;
            }
            __syncthreads();
            if (tid < 24) {
                float a = biasg[tid];
#pragma unroll
                for (int g2 = 0; g2 < 8; ++g2) a += redG[tid][g2];
                ghl[tid] = a;
            }
            // ---- hop 2: inp+applied (epoch s+1), batched: 4-5 words/thread ----
            {
                const int ep = s + 1;
                const ull okhi = ((ull)(unsigned)ep) << 32;
                ull v0, v1, v2, v3, v4;
                do {
                    v0 = gldll(&app_p[tid]);
                    v1 = gldll(&app_p[tid + 256]);
                    v2 = gldll(&app_p[tid + 512]);
                    v3 = gldll(&app_p[tid + 768]);
                    v4 = (tid < 8) ? gldll(&app_p[tid + 1024]) : okhi;
                } while (((int)(v0 >> 32) != ep) | ((int)(v1 >> 32) != ep) |
                         ((int)(v2 >> 32) != ep) | ((int)(v3 >> 32) != ep) |
                         ((int)(v4 >> 32) != ep));
                xl[tid]       = lowf(v0);
                xl[tid + 256] = lowf(v1);
                xl[tid + 512] = lowf(v2);
                xl[tid + 768] = lowf(v3);
                if (tid < 8) xl[tid + 1024] = lowf(v4);
            }
            __syncthreads();
            {   // o = relu(comb_W @ [inp; applied]) ; k = 4sc + 128i + r
                float b = 0.f;
#pragma unroll
                for (int i = 0; i < 9; ++i) {
                    float4 w = wc4[i];
                    float4 x4 = *(const float4*)&xl[4 * sc + 128 * i];
                    b += w.x*x4.x + w.y*x4.y + w.z*x4.z + w.w*x4.w;
                }
                redC[rc][sc] = b;
            }
            __syncthreads();
            if (tid < 8) {
                float a = biasc[tid];
#pragma unroll
                for (int g2 = 0; g2 < 32; ++g2) a += redC[tid][g2];
                gstll(&obuf_p[dbase + tid], packfe(fmaxf(a, 0.f), s + 1));
            }
            // ---- hop 3: o all-gather (epoch s+1), batched: 2 words/thread ----
            {
                const int ep = s + 1;
                ull v0, v1;
                do {
                    v0 = gldll(&obuf_p[tid]);
                    v1 = gldll(&obuf_p[tid + 256]);
                } while (((int)(v0 >> 32) != ep) | ((int)(v1 >> 32) != ep));
                xl[tid]       = lowf(v0);
                xl[tid + 256] = lowf(v1);
            }
            __syncthreads();
            {   // gi = gWih @ o
                float a = 0.f;
#pragma unroll
                for (int j = 0; j < 16; ++j) {
                    float4 w = wi4[j];
                    float4 o4 = *(const float4*)&xl[4 * sg + 32 * j];
                    a += w.x*o4.x + w.y*o4.y + w.z*o4.z + w.w*o4.w;
                }
                redG[rg][sg] = a;
            }
            __syncthreads();
            if (tid < 24) {
                float a = biasi[tid];
#pragma unroll
                for (int g2 = 0; g2 < 8; ++g2) a += redG[tid][g2];
                gil[tid] = a;
            }
            __syncthreads();
            if (tid < 8) {
                float r_ = sigf(gil[tid] + ghl[tid]);
                float z_ = sigf(gil[8 + tid] + ghl[8 + tid]);
                float n_ = tanh_f(gil[16 + tid] + r_ * ghl[16 + tid]);
                float hnew = (1.f - z_) * n_ + z_ * hx[8 + dbase + tid];
                gstll(&hdec_p[dbase + tid], packfe(hnew, s + 1));
            }
            __syncthreads();   // protect hx before next-step overwrite
        }
    }

    // epilogue: logits for s=29 (block 0)
    if (bid == 0) {
        {
            ull v0, v1;
            do {
                v0 = gldll(&hdec_p[tid]);
                v1 = gldll(&hdec_p[tid + 256]);
            } while (((int)(v0 >> 32) != 30) | ((int)(v1 >> 32) != 30));
            hx[8 + tid]       = lowf(v0);
            hx[8 + tid + 256] = lowf(v1);
        }
        __syncthreads();
        {
            float a = 0.f;
#pragma unroll
            for (int i = 0; i < 4; ++i) {
                float4 w = wo4[i];
                float4 h4 = *(const float4*)&hx[8 + 4 * so + 128 * i];
                a += w.x*h4.x + w.y*h4.y + w.z*h4.z + w.w*h4.w;
            }
            redO[ro][so] = a;
        }
        __syncthreads();
        if (tid < 8) {
            float a = outb[tid];
#pragma unroll
            for (int g2 = 0; g2 < 32; ++g2) a += redO[tid][g2];
            float m = a;
            m = fmaxf(m, __shfl_xor(m, 1));
            m = fmaxf(m, __shfl_xor(m, 2));
            m = fmaxf(m, __shfl_xor(m, 4));
            float e = __expf(a - m);
            float ss = e;
            ss += __shfl_xor(ss, 1);
            ss += __shfl_xor(ss, 2);
            ss += __shfl_xor(ss, 4);
            dout[29 * 8 + tid] = a - m - __logf(ss);
        }
    }
}

// ---------------------------------------------------------------------------
extern "C" void kernel_launch(void* const* d_in, const int* in_sizes, int n_in,
                              void* d_out, int out_size, void* d_ws, size_t ws_size,
                              hipStream_t stream) {
    (void)in_sizes; (void)n_in; (void)out_size; (void)ws_size;
    const float* data    = (const float*)d_in[0];
    const float* enc_Wih = (const float*)d_in[1];
    const float* enc_Whh = (const float*)d_in[2];
    const float* enc_bih = (const float*)d_in[3];
    const float* enc_bhh = (const float*)d_in[4];
    const float* p1f_Wih = (const float*)d_in[5];
    const float* p1f_Whh = (const float*)d_in[6];
    const float* p1f_bih = (const float*)d_in[7];
    const float* p1f_bhh = (const float*)d_in[8];
    const float* p1b_Wih = (const float*)d_in[9];
    const float* p1b_Whh = (const float*)d_in[10];
    const float* p1b_bih = (const float*)d_in[11];
    const float* p1b_bhh = (const float*)d_in[12];
    const float* p2f_Wih = (const float*)d_in[13];
    const float* p2f_Whh = (const float*)d_in[14];
    const float* p2f_bih = (const float*)d_in[15];
    const float* p2f_bhh = (const float*)d_in[16];
    const float* p2b_Wih = (const float*)d_in[17];
    const float* p2b_Whh = (const float*)d_in[18];
    const float* p2b_bih = (const float*)d_in[19];
    const float* p2b_bhh = (const float*)d_in[20];
    const float* attn_W  = (const float*)d_in[21];
    const float* attn_b  = (const float*)d_in[22];
    const float* comb_W  = (const float*)d_in[23];
    const float* comb_b  = (const float*)d_in[24];
    const float* gru_Wih = (const float*)d_in[25];
    const float* gru_Whh = (const float*)d_in[26];
    const float* gru_bih = (const float*)d_in[27];
    const float* gru_bhh = (const float*)d_in[28];
    const float* out_W   = (const float*)d_in[29];
    const float* out_b   = (const float*)d_in[30];

    float* ws = (float*)d_ws;
    // zeroed region [0 .. 142864)
    ull* hbufF   = (ull*)ws;                 // 122880 floats (61440 ull)
    int* flagsE  = (int*)(ws + 122880);      // 7680
    ull* hp1     = (ull*)(ws + 130560);      // 4096 floats = [2][2][512] ull
    ull* hp2     = (ull*)(ws + 134656);      // 4096 floats
    ull* hdec_p  = (ull*)(ws + 138752);      // 1024 floats = 512 ull
    ull* app_p   = (ull*)(ws + 139776);      // 2064 floats = 1032 ull
    ull* obuf_p  = (ull*)(ws + 141840);      // 1024 floats = 512 ull -> end 142864
    // non-zeroed scratch
    float* henc  = ws + 142864;              // 122880
    float* xp1f  = ws + 265744;              // 245760
    float* xp1b  = ws + 511504;              // 245760
    float* f1    = ws + 757264;              // 61440
    float* b1o   = ws + 818704;              // 61440
    float* x2    = ws + 880144;              // 122880
    float* xp2f  = ws + 1003024;             // 122880
    float* xp2b  = ws + 1125904;             // 122880
    float* f2    = ws + 1248784;             // 30720
    float* b2o   = ws + 1279504;             // 30720
    float* ctxb  = ws + 1310224;             // 61440

    init_k<<<256, 256, 0, stream>>>(ws);

    enc_all<<<240, 256, 0, stream>>>(data, enc_Wih, enc_Whh, enc_bih, enc_bhh,
                                     hbufF, henc, flagsE);
    gemm_xp<<<128, 256, 0, stream>>>(henc, 120, 1024, 0, p1f_Wih, p1f_bih, p1f_bhh, xp1f);
    gemm_xp<<<128, 256, 0, stream>>>(henc, 120, 1024, 1, p1b_Wih, p1b_bih, p1b_bhh, xp1b);
    pyr_rec<<<128, 256, 0, stream>>>(xp1f, xp1b, p1f_Whh, p1b_Whh, hp1, f1, b1o, 120);
    x2_assemble<<<60, 256, 0, stream>>>(f1, b1o, x2);
    gemm_xp<<<64, 256, 0, stream>>>(x2, 60, 2048, 0, p2f_Wih, p2f_bih, p2f_bhh, xp2f);
    gemm_xp<<<64, 256, 0, stream>>>(x2, 60, 2048, 1, p2b_Wih, p2b_bih, p2b_bhh, xp2b);
    pyr_rec<<<128, 256, 0, stream>>>(xp2f, xp2b, p2f_Whh, p2b_Whh, hp2, f2, b2o, 60);
    ctx_k<<<60, 256, 0, stream>>>(f2, b2o, ctxb, hdec_p);
    dec_k<<<66, 256, 0, stream>>>(attn_W, attn_b, comb_W, comb_b,
                                  gru_Wih, gru_Whh, gru_bih, gru_bhh,
                                  out_W, out_b, ctxb, hdec_p, app_p, obuf_p,
                                  (float*)d_out);
}

// Round 2
// 1717.696 us; speedup vs baseline: 1.0830x; 1.0315x over previous
//
#include <hip/hip_runtime.h>
#include <math.h>

// Model dims: H=512 D=128 L=8 T=64 W=240 CTX=60 NSTEPS=30

typedef __attribute__((ext_vector_type(8))) short short8;
typedef __attribute__((ext_vector_type(4))) float floatx4;
typedef unsigned long long ull;

__device__ __forceinline__ float sigf(float x) { return 1.f / (1.f + __expf(-x)); }
__device__ __forceinline__ float tanh_f(float x) {
    float e = __expf(2.f * x);
    return 1.f - 2.f / (e + 1.f);
}
__device__ __forceinline__ unsigned short f2b(float x) {   // fp32 -> bf16 RNE
    unsigned u = __float_as_uint(x);
    unsigned r = (u + 0x7FFFu + ((u >> 16) & 1u)) >> 16;
    return (unsigned short)r;
}

// RELAXED agent-scope atomics only (acquire/release emit buffer_inv/wbl2 on
// gfx950 and trash the XCD L2). Cross-block payloads are {epoch|data} ull
// words polled directly (data+readiness in one MALL round trip). Polls are
// BATCHED (independent loads in one loop body). R8: the decoder is
// restructured so the ONLY cross-block payload per step is the h all-to-all
// (1 RT/step, was 3): applied-space is folded into a precomputed
// M = comb_W[:,8:] @ ctx^T (512x60) that lives in LDS of every block, so
// attention, softmax, o, logits are all computed redundantly per block.
// h uses a parity double-buffer [2][512]; exact-epoch matching is safe by
// mutual gating: overwriting slot p epoch e+2 requires a full poll of slot
// p^1 epoch e+1, whose writers each completed their poll of slot p epoch e.
__device__ __forceinline__ float gld(const float* p) {
    return __hip_atomic_load(p, __ATOMIC_RELAXED, __HIP_MEMORY_SCOPE_AGENT);
}
__device__ __forceinline__ void gst(float* p, float v) {
    __hip_atomic_store(p, v, __ATOMIC_RELAXED, __HIP_MEMORY_SCOPE_AGENT);
}
__device__ __forceinline__ ull gldll(const ull* p) {
    return __hip_atomic_load(p, __ATOMIC_RELAXED, __HIP_MEMORY_SCOPE_AGENT);
}
__device__ __forceinline__ void gstll(ull* p, ull v) {
    __hip_atomic_store(p, v, __ATOMIC_RELAXED, __HIP_MEMORY_SCOPE_AGENT);
}
__device__ __forceinline__ ull packfe(float d, int ep) {
    return ((ull)(unsigned)ep << 32) | (ull)__float_as_uint(d);
}
__device__ __forceinline__ float lowf(ull v) { return __uint_as_float((unsigned)v); }
__device__ __forceinline__ void set_flag(int* f, int v) {
    __hip_atomic_store(f, v, __ATOMIC_RELAXED, __HIP_MEMORY_SCOPE_AGENT);
}
__device__ __forceinline__ void wait_flag_ge(int* f, int ep) {
    while (__hip_atomic_load(f, __ATOMIC_RELAXED, __HIP_MEMORY_SCOPE_AGENT) < ep)
        __builtin_amdgcn_s_sleep(1);
}

// ---------------------------------------------------------------------------
// init: zero [hbufF | flagsE | hp1 | hp2 | hdec_p(2 slots)] = 140800 f
// ---------------------------------------------------------------------------
__global__ void init_k(float* __restrict__ ws) {
    for (int i = blockIdx.x * blockDim.x + threadIdx.x; i < 140800; i += gridDim.x * blockDim.x)
        ws[i] = 0.f;
}

// ---------------------------------------------------------------------------
// Encoder, ONE persistent launch, 64 steps, bf16 MFMA (unchanged).
// ---------------------------------------------------------------------------
__global__ void __launch_bounds__(256, 1) enc_all(
    const float* __restrict__ data,
    const float* __restrict__ Wih, const float* __restrict__ Whh,
    const float* __restrict__ bih, const float* __restrict__ bhh,
    ull* __restrict__ hbufF,        // [2][15][16][64] x (2 ull)
    float* __restrict__ henc,       // [240][512] fp32 final h
    int* __restrict__ flags)        // [240][32]
{
    __shared__ short act2[20 * 64 * 8];
    __shared__ float gw[4][640];
    __shared__ float cs[512];
    __shared__ short hw[4][16][8];
    __shared__ float biasL[4][4][8];

    const int tid = threadIdx.x;
    const int fg = blockIdx.x >> 4, ds = blockIdx.x & 15;
    const int w = tid >> 6, lane = tid & 63;
    const int n = lane & 15, q = lane >> 4;

    short8 bfrag[2][20];
#pragma unroll
    for (int nt = 0; nt < 2; ++nt) {
        int rr = nt * 16 + n;
        int g = rr >> 3, dp = rr & 7;
        int grow = g * 512 + ds * 32 + w * 8 + dp;
#pragma unroll
        for (int kt = 0; kt < 20; ++kt) {
            int k0 = kt * 32 + q * 8;
            const float* src = (k0 < 512) ? (Whh + (size_t)grow * 512 + k0)
                                          : (Wih + (size_t)grow * 128 + (k0 - 512));
            float4 lo = *(const float4*)src;
            float4 hi = *(const float4*)(src + 4);
            short8 bf;
            bf[0] = (short)f2b(lo.x); bf[1] = (short)f2b(lo.y);
            bf[2] = (short)f2b(lo.z); bf[3] = (short)f2b(lo.w);
            bf[4] = (short)f2b(hi.x); bf[5] = (short)f2b(hi.y);
            bf[6] = (short)f2b(hi.z); bf[7] = (short)f2b(hi.w);
            bfrag[nt][kt] = bf;
        }
    }
    if (tid < 128) {
        int w2 = tid >> 5, rr = tid & 31;
        int g = rr >> 3, dp = rr & 7;
        int grow = g * 512 + ds * 32 + w2 * 8 + dp;
        biasL[w2][g][dp] = bih[grow] + bhh[grow];
    }
    for (int i = tid; i < 512; i += 256) cs[i] = 0.f;
    __syncthreads();

    ull* a2ll = (ull*)act2;

    for (int t = 0; t < 64; ++t) {
        if (t > 0) {
            if (tid < 16) wait_flag_ge(&flags[(fg * 16 + tid) * 32], t);
        }
        __syncthreads();

        {
            const ull* hsrc = hbufF + (size_t)(((t & 1) * 15 + fg) * 16) * 64 * 2;
            for (int i = tid; i < 2048; i += 256) a2ll[i] = gldll(hsrc + i);
            int kt2 = tid >> 6, l2 = tid & 63, f2 = l2 & 15, q2 = l2 >> 4;
            const float* xs = data + ((size_t)t * 240 + fg * 16 + f2) * 128 + kt2 * 32 + q2 * 8;
            float4 lo = *(const float4*)xs;
            float4 hi = *(const float4*)(xs + 4);
            short8 xp;
            xp[0] = (short)f2b(lo.x); xp[1] = (short)f2b(lo.y);
            xp[2] = (short)f2b(lo.z); xp[3] = (short)f2b(lo.w);
            xp[4] = (short)f2b(hi.x); xp[5] = (short)f2b(hi.y);
            xp[6] = (short)f2b(hi.z); xp[7] = (short)f2b(hi.w);
            *(short8*)&act2[((16 + kt2) * 64 + l2) * 8] = xp;
        }
        __syncthreads();

        floatx4 acc0 = {0.f, 0.f, 0.f, 0.f};
        floatx4 acc1 = {0.f, 0.f, 0.f, 0.f};
#pragma unroll
        for (int kt = 0; kt < 20; ++kt) {
            short8 a = *(short8*)&act2[(kt * 64 + lane) * 8];
            acc0 = __builtin_amdgcn_mfma_f32_16x16x32_bf16(a, bfrag[0][kt], acc0, 0, 0, 0);
            acc1 = __builtin_amdgcn_mfma_f32_16x16x32_bf16(a, bfrag[1][kt], acc1, 0, 0, 0);
        }
        *(floatx4*)&gw[w][(0 * 16 + n) * 20 + 4 * q] = acc0;
        *(floatx4*)&gw[w][(1 * 16 + n) * 20 + 4 * q] = acc1;

        int nb = (t + 1) & 1;
#pragma unroll
        for (int it = 0; it < 2; ++it) {
            int f = lane & 15, dp = q + 4 * it;
            float gi = gw[w][(0 * 8 + dp) * 20 + f] + biasL[w][0][dp];
            float gf = gw[w][(1 * 8 + dp) * 20 + f] + biasL[w][1][dp];
            float gg = gw[w][(2 * 8 + dp) * 20 + f] + biasL[w][2][dp];
            float go = gw[w][(3 * 8 + dp) * 20 + f] + biasL[w][3][dp];
            int ci = f * 32 + w * 8 + dp;
            float cc = cs[ci];
            float cn = sigf(gf) * cc + sigf(gi) * tanh_f(gg);
            float hn = sigf(go) * tanh_f(cn);
            cs[ci] = cn;
            hw[w][f][dp] = (short)f2b(hn);
            if (t == 63)
                gst(&henc[(size_t)(fg * 16 + f) * 512 + ds * 32 + w * 8 + dp], hn);
        }
        if (lane < 16) {
            const ull* hwp = (const ull*)&hw[w][lane][0];
            ull* dst = hbufF + (size_t)((((nb * 15 + fg) * 16 + ds) * 64) + w * 16 + lane) * 2;
            gstll(dst + 0, hwp[0]); gstll(dst + 1, hwp[1]);
        }
        __syncthreads();
        if (tid == 0) set_flag(&flags[(fg * 16 + ds) * 32], t + 1);
    }
}

// ---------------------------------------------------------------------------
// xp GEMM (unchanged)
// ---------------------------------------------------------------------------
__global__ void __launch_bounds__(256) gemm_xp(
    const float* __restrict__ A, int M, int K, int rev,
    const float* __restrict__ Wv, const float* __restrict__ ba, const float* __restrict__ bb,
    float* __restrict__ C)
{
    __shared__ float At[16][66];
    __shared__ float Wt[128][66];
    const int tid = threadIdx.x;
    const int nt = blockIdx.x & 15, mt = blockIdx.x >> 4;
    const int rp = tid >> 2, fq = tid & 3;
    const int lr0 = 2 * rp, lr1 = lr0 + 1;
    const int n0 = nt * 128 + lr0, n1 = n0 + 1;

    float acc0[4], acc1[4];
    {
        float b0 = ba[n0] + bb[n0], b1 = ba[n1] + bb[n1];
#pragma unroll
        for (int j = 0; j < 4; ++j) { acc0[j] = b0; acc1[j] = b1; }
    }

    for (int kt = 0; kt < K; kt += 64) {
        {
            int f = tid >> 4, c4 = tid & 15;
            int m = mt * 16 + f;
            float4 v = make_float4(0.f, 0.f, 0.f, 0.f);
            if (m < M) {
                int ar = rev ? (M - 1 - m) : m;
                v = ((const float4*)(A + (size_t)ar * K + kt))[c4];
            }
            At[f][c4 * 4 + 0] = v.x; At[f][c4 * 4 + 1] = v.y;
            At[f][c4 * 4 + 2] = v.z; At[f][c4 * 4 + 3] = v.w;
        }
        for (int i = tid; i < 2048; i += 256) {
            int lr = i >> 4, c4 = i & 15;
            float4 v = ((const float4*)(Wv + (size_t)(nt * 128 + lr) * K + kt))[c4];
            Wt[lr][c4 * 4 + 0] = v.x; Wt[lr][c4 * 4 + 1] = v.y;
            Wt[lr][c4 * 4 + 2] = v.z; Wt[lr][c4 * 4 + 3] = v.w;
        }
        __syncthreads();
        const float2* w0p = (const float2*)(&Wt[lr0][0]);
        const float2* w1p = (const float2*)(&Wt[lr1][0]);
#pragma unroll 8
        for (int kh = 0; kh < 32; ++kh) {
            float2 w0 = w0p[kh], w1 = w1p[kh];
#pragma unroll
            for (int j = 0; j < 4; ++j) {
                float2 av = ((const float2*)(&At[4 * fq + j][0]))[kh];
                acc0[j] += w0.x * av.x + w0.y * av.y;
                acc1[j] += w1.x * av.x + w1.y * av.y;
            }
        }
        __syncthreads();
    }
#pragma unroll
    for (int j = 0; j < 4; ++j) {
        int m = mt * 16 + 4 * fq + j;
        if (m < M) {
            C[(size_t)m * 2048 + n0] = acc0[j];
            C[(size_t)m * 2048 + n1] = acc1[j];
        }
    }
}

// ---------------------------------------------------------------------------
// Pyramidal bi-LSTM (unchanged from R7: batched h poll, 1 RT/step).
// ---------------------------------------------------------------------------
__global__ void __launch_bounds__(256, 1) pyr_rec(
    const float* __restrict__ xpF, const float* __restrict__ xpB,
    const float* __restrict__ WhhF, const float* __restrict__ WhhB,
    ull* __restrict__ hp,      // [dir][2][512]
    float* __restrict__ outF, float* __restrict__ outB,
    int steps)
{
    const int tid = threadIdx.x;
    const int dir = blockIdx.x >> 6, blk = blockIdx.x & 63;
    const float* xp  = dir ? xpB : xpF;
    const float* Whh = dir ? WhhB : WhhF;
    float* outp = dir ? outB : outF;
    ull* hpd = hp + (size_t)dir * 1024;

    __shared__ __align__(16) float hcur[512];
    __shared__ float red[32][9];
    __shared__ float gv[32];

    const int lr = tid & 31, seg = tid >> 5;
    const int grow = (lr >> 3) * 512 + blk * 8 + (lr & 7);
    float4 wl4[16];
#pragma unroll
    for (int j = 0; j < 16; ++j)
        wl4[j] = *(const float4*)&Whh[(size_t)grow * 512 + 4 * seg + 32 * j];

    const int growx = (tid >> 3) * 512 + blk * 8 + (tid & 7);   // for tid<32
    float creg = 0.f;
    __syncthreads();

    for (int t = 0; t < steps; ++t) {
        float xg = 0.f;
        if (tid < 32) xg = xp[(size_t)t * 2048 + growx];   // prefetch (no h dep)
        {
            const ull* base = hpd + (size_t)(t & 1) * 512;
            ull v0, v1;
            do {
                v0 = gldll(base + tid);
                v1 = gldll(base + tid + 256);
            } while (((int)(v0 >> 32) != t) | ((int)(v1 >> 32) != t));
            hcur[tid]       = lowf(v0);
            hcur[tid + 256] = lowf(v1);
        }
        __syncthreads();

        float a = 0.f;
#pragma unroll
        for (int j = 0; j < 16; ++j) {
            float4 w = wl4[j];
            float4 h4 = *(const float4*)&hcur[4 * seg + 32 * j];
            a += w.x*h4.x + w.y*h4.y + w.z*h4.z + w.w*h4.w;
        }
        red[lr][seg] = a;
        __syncthreads();

        if (tid < 32) {
            float g = xg;
#pragma unroll
            for (int s2 = 0; s2 < 8; ++s2) g += red[tid][s2];
            gv[tid] = g;
        }
        __syncthreads();
        if (tid < 8) {
            float i_ = sigf(gv[tid]), f_ = sigf(gv[8 + tid]);
            float g_ = tanh_f(gv[16 + tid]), o_ = sigf(gv[24 + tid]);
            creg = f_ * creg + i_ * g_;
            float hn = o_ * tanh_f(creg);
            int d = blk * 8 + tid;
            gstll(&hpd[((t + 1) & 1) * 512 + d], packfe(hn, t + 1));
            int row = dir ? (steps - 1 - t) : t;
            outp[(size_t)row * 512 + d] = hn;
        }
        __syncthreads();
    }
}

__global__ void x2_assemble(const float* __restrict__ f1, const float* __restrict__ b1o,
                            float* __restrict__ x2)
{
    int j = blockIdx.x;
    for (int k = threadIdx.x; k < 2048; k += 256) {
        int q = k >> 9, r = k & 511;
        const float* src = (q & 1) ? b1o : f1;
        int row = 2 * j + (q >> 1);
        x2[(size_t)j * 2048 + k] = src[(size_t)row * 512 + r];
    }
}

// ctx assemble + publish hdec slot 0 with epoch 0
__global__ void ctx_k(const float* __restrict__ f2, const float* __restrict__ b2o,
                      float* __restrict__ ctx, ull* __restrict__ hdec_p)
{
    int j = blockIdx.x;
    for (int k = threadIdx.x; k < 1024; k += 256)
        ctx[(size_t)j * 1024 + k] = (k < 512) ? f2[(size_t)j * 512 + k]
                                              : b2o[(size_t)j * 512 + k - 512];
    if (j == 0) {
        for (int i = threadIdx.x; i < 512; i += 256)
            hdec_p[i] = packfe(f2[59 * 512 + i], 0);
    }
}

// ---------------------------------------------------------------------------
// R8: precompute M = comb_W[:, 8:1032] @ ctx^T  -> Mg[512][60]
// Folds the attention-apply + comb matvec into one 512x60 matrix so the
// decoder never needs the 1024-dim 'applied' vector.
// ---------------------------------------------------------------------------
__global__ void __launch_bounds__(256) precomp_M(
    const float* __restrict__ comb_W,   // [512][1032]
    const float* __restrict__ ctx,      // [60][1024]
    float* __restrict__ Mg)             // [512][60]
{
    __shared__ float cw[8 * 1024];      // 32 KB: comb_W rows d0..d0+8, cols 8..1032
    const int tid = threadIdx.x, d0 = blockIdx.x * 8;
    for (int i = tid; i < 2048; i += 256) {
        int r = i >> 8, c4 = i & 255;
        float4 v = *(const float4*)&comb_W[(size_t)(d0 + r) * 1032 + 8 + 4 * c4];
        *(float4*)&cw[r * 1024 + 4 * c4] = v;
    }
    __syncthreads();
    for (int o = tid; o < 480; o += 256) {
        int dl = o / 60, j = o % 60;
        const float4* cp = (const float4*)&cw[dl * 1024];
        const float4* xp = (const float4*)(ctx + (size_t)j * 1024);
        float a = 0.f;
#pragma unroll 4
        for (int k = 0; k < 256; ++k) {
            float4 w = cp[k], x = xp[k];
            a += w.x * x.x + w.y * x.y + w.z * x.z + w.w * x.w;
        }
        Mg[(size_t)(d0 + dl) * 60 + j] = a;
    }
}

// ---------------------------------------------------------------------------
// Decoder R8: 64 identical blocks, 8 h-dims each. Everything except the two
// partitioned GRU matvecs is replicated per block (attn_W/outW in regs,
// M(+inp cols of comb_W) in LDS), so the ONLY cross-block payload per step is
// the h all-to-all: 1 MALL RT/step (was 3). Parity double-buffered h with
// exact-epoch words (mutual-gating safety — see header comment).
// ---------------------------------------------------------------------------
__global__ void __launch_bounds__(256, 1) dec_k(
    const float* __restrict__ attn_W, const float* __restrict__ attn_b,
    const float* __restrict__ comb_W, const float* __restrict__ comb_b,
    const float* __restrict__ gWih, const float* __restrict__ gWhh,
    const float* __restrict__ gbih, const float* __restrict__ gbhh,
    const float* __restrict__ outW, const float* __restrict__ outb,
    const float* __restrict__ Mg,   // [512][60]
    ull* __restrict__ hdec_p,       // [2][512]
    float* __restrict__ dout)
{
    const int tid = threadIdx.x, bid = blockIdx.x;   // 64 blocks
    const int dbase = bid * 8;

    __shared__ float M2[512][70];                    // cols: [M(60) | Minp(8) | pad2]
    __shared__ __align__(16) float hx[528];          // [inp(8); h(512); pad0(8)]
    __shared__ __align__(16) float xl[512];          // o
    __shared__ __align__(8) float awx[68];           // [aw(60); inp(8)]
    __shared__ float redA[64][5];
    __shared__ float redGH[32][9];
    __shared__ float redG[32][9];
    __shared__ float redO[8][33];
    __shared__ float biasg[24], biasi[24];
    __shared__ float cbL[512];
    __shared__ float attnbL[64];

    float4 wa4[33], wo4[4], wg4[16], wi4[16];
    const int rz = tid >> 2, sz = tid & 3;  // z: 60(64) rows x 4 segs
    const int ro = tid >> 5, so = tid & 31; // logits: 8 rows x 32 segs
    const int rg = tid >> 3, sg = tid & 7;  // gh/gi: 24(32) rows x 8 segs

    // ---- weights to registers (every block holds ALL roles) ----
    {
        int rr = (rz < 60) ? rz : 59;
#pragma unroll
        for (int i = 0; i < 32; ++i)
            wa4[i] = *(const float4*)&attn_W[(size_t)rr * 520 + 4 * sz + 16 * i];
        float* wap = (float*)&wa4[32];
#pragma unroll
        for (int r = 0; r < 4; ++r) {
            int k = 4 * sz + 512 + r;
            wap[r] = (k < 520) ? attn_W[(size_t)rr * 520 + k] : 0.f;
        }
    }
#pragma unroll
    for (int i = 0; i < 4; ++i)
        wo4[i] = *(const float4*)&outW[(size_t)ro * 512 + 4 * so + 128 * i];
    {
        int rr = (rg < 24) ? rg : 23;
        int grow = (rr >> 3) * 512 + dbase + (rr & 7);
#pragma unroll
        for (int j = 0; j < 16; ++j) {
            wg4[j] = *(const float4*)&gWhh[(size_t)grow * 512 + 4 * sg + 32 * j];
            wi4[j] = *(const float4*)&gWih[(size_t)grow * 512 + 4 * sg + 32 * j];
        }
    }
    if (tid < 24) {
        int g2 = (tid >> 3) * 512 + dbase + (tid & 7);
        biasg[tid] = gbhh[g2];
        biasi[tid] = gbih[g2];
    }
    for (int i = tid; i < 512; i += 256) cbL[i] = comb_b[i];
    if (tid < 64) attnbL[tid] = (tid < 60) ? attn_b[tid] : 0.f;
    if (tid < 8) hx[520 + tid] = 0.f;
    // M2 load: cols 0..59 from Mg, cols 60..67 = comb_W[:,0..8)
    for (int i = tid; i < 512 * 15; i += 256) {
        int r = i / 15, c4 = i % 15;
        float4 v = *(const float4*)&Mg[(size_t)r * 60 + 4 * c4];
        M2[r][4 * c4 + 0] = v.x; M2[r][4 * c4 + 1] = v.y;
        M2[r][4 * c4 + 2] = v.z; M2[r][4 * c4 + 3] = v.w;
    }
    for (int i = tid; i < 512 * 2; i += 256) {
        int r = i >> 1, h4 = i & 1;
        float4 v = *(const float4*)&comb_W[(size_t)r * 1032 + 4 * h4];
        M2[r][60 + 4 * h4 + 0] = v.x; M2[r][60 + 4 * h4 + 1] = v.y;
        M2[r][60 + 4 * h4 + 2] = v.z; M2[r][60 + 4 * h4 + 3] = v.w;
    }
    __syncthreads();

    for (int s = 0; s < 30; ++s) {
        // ---- the ONE cross-block hop: h (slot s&1, epoch s), batched poll ----
        {
            const ull* hs = hdec_p + (size_t)(s & 1) * 512;
            ull v0, v1;
            do {
                v0 = gldll(hs + tid);
                v1 = gldll(hs + tid + 256);
            } while (((int)(v0 >> 32) != s) | ((int)(v1 >> 32) != s));
            hx[8 + tid]       = lowf(v0);
            hx[8 + tid + 256] = lowf(v1);
        }
        __syncthreads();

        // phase A: logits partial (s>0) + gh partial (both need only h)
        if (s > 0) {
            float a = 0.f;
#pragma unroll
            for (int i = 0; i < 4; ++i) {
                float4 w = wo4[i];
                float4 h4 = *(const float4*)&hx[8 + 4 * so + 128 * i];
                a += w.x*h4.x + w.y*h4.y + w.z*h4.z + w.w*h4.w;
            }
            redO[ro][so] = a;
        }
        {
            float a = 0.f;
#pragma unroll
            for (int j = 0; j < 16; ++j) {
                float4 w = wg4[j];
                float4 h4 = *(const float4*)&hx[8 + 4 * sg + 32 * j];
                a += w.x*h4.x + w.y*h4.y + w.z*h4.z + w.w*h4.w;
            }
            redGH[rg][sg] = a;
        }
        __syncthreads();

        // phase B: inp = log_softmax(outW@h) (or one-hot at s=0), lanes 0..7
        if (tid < 8) {
            float v;
            if (s > 0) {
                float a = outb[tid];
#pragma unroll
                for (int g2 = 0; g2 < 32; ++g2) a += redO[tid][g2];
                float m = a;
                m = fmaxf(m, __shfl_xor(m, 1));
                m = fmaxf(m, __shfl_xor(m, 2));
                m = fmaxf(m, __shfl_xor(m, 4));
                float e = __expf(a - m);
                float ss2 = e;
                ss2 += __shfl_xor(ss2, 1);
                ss2 += __shfl_xor(ss2, 2);
                ss2 += __shfl_xor(ss2, 4);
                v = a - m - __logf(ss2);
                if (bid == 0) dout[(s - 1) * 8 + tid] = v;
            } else {
                v = (tid == 7) ? 1.f : 0.f;
            }
            hx[tid] = v;
            awx[60 + tid] = v;
        }
        __syncthreads();

        // phase C: z partial = attn_W @ [inp; h]
        {
            float a = 0.f;
#pragma unroll
            for (int i = 0; i < 33; ++i) {
                float4 w = wa4[i];
                float4 x4 = *(const float4*)&hx[4 * sz + 16 * i];
                a += w.x*x4.x + w.y*x4.y + w.z*x4.z + w.w*x4.w;
            }
            redA[rz][sz] = a;
        }
        __syncthreads();

        // phase D: wave-0 parallel 60-wide softmax -> awx[0..60)
        if (tid < 64) {
            float z = -1e30f;
            if (tid < 60)
                z = attnbL[tid] + redA[tid][0] + redA[tid][1] + redA[tid][2] + redA[tid][3];
            float m = z;
#pragma unroll
            for (int off = 32; off; off >>= 1) m = fmaxf(m, __shfl_xor(m, off));
            float e = (tid < 60) ? __expf(z - m) : 0.f;
            float ss2 = e;
#pragma unroll
            for (int off = 32; off; off >>= 1) ss2 += __shfl_xor(ss2, off);
            if (tid < 60) awx[tid] = e / ss2;
        }
        __syncthreads();

        // phase E: o = relu(M2 @ [aw; inp] + comb_b), 2 dims/thread
#pragma unroll
        for (int half = 0; half < 2; ++half) {
            int c = tid + half * 256;
            float a = cbL[c];
            const float2* mrow = (const float2*)&M2[c][0];
            const float2* xv = (const float2*)&awx[0];
#pragma unroll
            for (int jj = 0; jj < 34; ++jj) {
                float2 mm = mrow[jj], xx = xv[jj];
                a += mm.x * xx.x + mm.y * xx.y;
            }
            xl[c] = fmaxf(a, 0.f);
        }
        __syncthreads();

        // phase F: gi partial = gWih @ o
        {
            float a = 0.f;
#pragma unroll
            for (int j = 0; j < 16; ++j) {
                float4 w = wi4[j];
                float4 o4 = *(const float4*)&xl[4 * sg + 32 * j];
                a += w.x*o4.x + w.y*o4.y + w.z*o4.z + w.w*o4.w;
            }
            redG[rg][sg] = a;
        }
        __syncthreads();

        // phase G: reduce + GRU combine + publish (8 threads, 3 gate rows each)
        if (tid < 8) {
            float gh0 = biasg[tid], gh1 = biasg[8 + tid], gh2 = biasg[16 + tid];
            float gi0 = biasi[tid], gi1 = biasi[8 + tid], gi2 = biasi[16 + tid];
#pragma unroll
            for (int g2 = 0; g2 < 8; ++g2) {
                gh0 += redGH[tid][g2]; gh1 += redGH[8 + tid][g2]; gh2 += redGH[16 + tid][g2];
                gi0 += redG[tid][g2];  gi1 += redG[8 + tid][g2];  gi2 += redG[16 + tid][g2];
            }
            float r_ = sigf(gi0 + gh0);
            float z_ = sigf(gi1 + gh1);
            float n_ = tanh_f(gi2 + r_ * gh2);
            float hnew = (1.f - z_) * n_ + z_ * hx[8 + dbase + tid];
            gstll(&hdec_p[(size_t)((s + 1) & 1) * 512 + dbase + tid], packfe(hnew, s + 1));
        }
        __syncthreads();   // protect hx/awx/xl before next-step overwrite
    }

    // epilogue: logits for s=29 (block 0 only)
    if (bid == 0) {
        {
            const ull* hs = hdec_p + (size_t)(30 & 1) * 512;
            ull v0, v1;
            do {
                v0 = gldll(hs + tid);
                v1 = gldll(hs + tid + 256);
            } while (((int)(v0 >> 32) != 30) | ((int)(v1 >> 32) != 30));
            hx[8 + tid]       = lowf(v0);
            hx[8 + tid + 256] = lowf(v1);
        }
        __syncthreads();
        {
            float a = 0.f;
#pragma unroll
            for (int i = 0; i < 4; ++i) {
                float4 w = wo4[i];
                float4 h4 = *(const float4*)&hx[8 + 4 * so + 128 * i];
                a += w.x*h4.x + w.y*h4.y + w.z*h4.z + w.w*h4.w;
            }
            redO[ro][so] = a;
        }
        __syncthreads();
        if (tid < 8) {
            float a = outb[tid];
#pragma unroll
            for (int g2 = 0; g2 < 32; ++g2) a += redO[tid][g2];
            float m = a;
            m = fmaxf(m, __shfl_xor(m, 1));
            m = fmaxf(m, __shfl_xor(m, 2));
            m = fmaxf(m, __shfl_xor(m, 4));
            float e = __expf(a - m);
            float ss2 = e;
            ss2 += __shfl_xor(ss2, 1);
            ss2 += __shfl_xor(ss2, 2);
            ss2 += __shfl_xor(ss2, 4);
            dout[29 * 8 + tid] = a - m - __logf(ss2);
        }
    }
}

// ---------------------------------------------------------------------------
extern "C" void kernel_launch(void* const* d_in, const int* in_sizes, int n_in,
                              void* d_out, int out_size, void* d_ws, size_t ws_size,
                              hipStream_t stream) {
    (void)in_sizes; (void)n_in; (void)out_size; (void)ws_size;
    const float* data    = (const float*)d_in[0];
    const float* enc_Wih = (const float*)d_in[1];
    const float* enc_Whh = (const float*)d_in[2];
    const float* enc_bih = (const float*)d_in[3];
    const float* enc_bhh = (const float*)d_in[4];
    const float* p1f_Wih = (const float*)d_in[5];
    const float* p1f_Whh = (const float*)d_in[6];
    const float* p1f_bih = (const float*)d_in[7];
    const float* p1f_bhh = (const float*)d_in[8];
    const float* p1b_Wih = (const float*)d_in[9];
    const float* p1b_Whh = (const float*)d_in[10];
    const float* p1b_bih = (const float*)d_in[11];
    const float* p1b_bhh = (const float*)d_in[12];
    const float* p2f_Wih = (const float*)d_in[13];
    const float* p2f_Whh = (const float*)d_in[14];
    const float* p2f_bih = (const float*)d_in[15];
    const float* p2f_bhh = (const float*)d_in[16];
    const float* p2b_Wih = (const float*)d_in[17];
    const float* p2b_Whh = (const float*)d_in[18];
    const float* p2b_bih = (const float*)d_in[19];
    const float* p2b_bhh = (const float*)d_in[20];
    const float* attn_W  = (const float*)d_in[21];
    const float* attn_b  = (const float*)d_in[22];
    const float* comb_W  = (const float*)d_in[23];
    const float* comb_b  = (const float*)d_in[24];
    const float* gru_Wih = (const float*)d_in[25];
    const float* gru_Whh = (const float*)d_in[26];
    const float* gru_bih = (const float*)d_in[27];
    const float* gru_bhh = (const float*)d_in[28];
    const float* out_W   = (const float*)d_in[29];
    const float* out_b   = (const float*)d_in[30];

    float* ws = (float*)d_ws;
    // zeroed region [0 .. 140800)
    ull* hbufF   = (ull*)ws;                 // 122880 floats (61440 ull)
    int* flagsE  = (int*)(ws + 122880);      // 7680
    ull* hp1     = (ull*)(ws + 130560);      // 4096 floats = [2][2][512] ull
    ull* hp2     = (ull*)(ws + 134656);      // 4096 floats
    ull* hdec_p  = (ull*)(ws + 138752);      // 2048 floats = [2][512] ull -> end 140800
    // non-zeroed scratch
    float* henc  = ws + 140800;              // 122880
    float* xp1f  = ws + 263680;              // 245760
    float* xp1b  = ws + 509440;              // 245760
    float* f1    = ws + 755200;              // 61440
    float* b1o   = ws + 816640;              // 61440
    float* x2    = ws + 878080;              // 122880
    float* xp2f  = ws + 1000960;             // 122880
    float* xp2b  = ws + 1123840;             // 122880
    float* f2    = ws + 1246720;             // 30720
    float* b2o   = ws + 1277440;             // 30720
    float* ctxb  = ws + 1308160;             // 61440
    float* Mg    = ws + 1369600;             // 30720 -> end 1400320

    init_k<<<256, 256, 0, stream>>>(ws);

    enc_all<<<240, 256, 0, stream>>>(data, enc_Wih, enc_Whh, enc_bih, enc_bhh,
                                     hbufF, henc, flagsE);
    gemm_xp<<<128, 256, 0, stream>>>(henc, 120, 1024, 0, p1f_Wih, p1f_bih, p1f_bhh, xp1f);
    gemm_xp<<<128, 256, 0, stream>>>(henc, 120, 1024, 1, p1b_Wih, p1b_bih, p1b_bhh, xp1b);
    pyr_rec<<<128, 256, 0, stream>>>(xp1f, xp1b, p1f_Whh, p1b_Whh, hp1, f1, b1o, 120);
    x2_assemble<<<60, 256, 0, stream>>>(f1, b1o, x2);
    gemm_xp<<<64, 256, 0, stream>>>(x2, 60, 2048, 0, p2f_Wih, p2f_bih, p2f_bhh, xp2f);
    gemm_xp<<<64, 256, 0, stream>>>(x2, 60, 2048, 1, p2b_Wih, p2b_bih, p2b_bhh, xp2b);
    pyr_rec<<<128, 256, 0, stream>>>(xp2f, xp2b, p2f_Whh, p2b_Whh, hp2, f2, b2o, 60);
    ctx_k<<<60, 256, 0, stream>>>(f2, b2o, ctxb, hdec_p);
    precomp_M<<<64, 256, 0, stream>>>(comb_W, ctxb, Mg);
    dec_k<<<64, 256, 0, stream>>>(attn_W, attn_b, comb_W, comb_b,
                                  gru_Wih, gru_Whh, gru_bih, gru_bhh,
                                  out_W, out_b, Mg, hdec_p,
                                  (float*)d_out);
}

// Round 4
// 1318.481 us; speedup vs baseline: 1.4109x; 1.3028x over previous
//
#include <hip/hip_runtime.h>
#include <math.h>

// Model dims: H=512 D=128 L=8 T=64 W=240 CTX=60 NSTEPS=30

typedef __attribute__((ext_vector_type(8))) short short8;
typedef __attribute__((ext_vector_type(4))) float floatx4;
typedef unsigned long long ull;

__device__ __forceinline__ float sigf(float x) { return 1.f / (1.f + __expf(-x)); }
__device__ __forceinline__ float tanh_f(float x) {
    float e = __expf(2.f * x);
    return 1.f - 2.f / (e + 1.f);
}
__device__ __forceinline__ unsigned short f2b(float x) {   // fp32 -> bf16 RNE
    unsigned u = __float_as_uint(x);
    unsigned r = (u + 0x7FFFu + ((u >> 16) & 1u)) >> 16;
    return (unsigned short)r;
}

// RELAXED agent-scope atomics only (acquire/release emit buffer_inv/wbl2 on
// gfx950 and trash the XCD L2). Cross-block payloads are {epoch|data} ull
// words polled directly (data+readiness in one MALL round trip), with all of
// a thread's words batch-polled in one latency window. R9: the ENCODER's h
// exchange is now also epoch-fused — words carry {epoch32|2xbf16}, the
// separate flags array is gone, so the per-step chain is ONE round trip
// (was flag-poll RT + data RT). Safety = mutual gating: overwriting slot p
// epoch t+2 requires a full poll of slot p^1 epoch t+1, whose writers all
// completed their own full poll of slot p epoch t, so a matched word is
// stable under re-reads. Poll loops back off with s_sleep(1) after a failed
// check to reduce fabric pressure from ~32K concurrently spinning threads.
__device__ __forceinline__ float gld(const float* p) {
    return __hip_atomic_load(p, __ATOMIC_RELAXED, __HIP_MEMORY_SCOPE_AGENT);
}
__device__ __forceinline__ void gst(float* p, float v) {
    __hip_atomic_store(p, v, __ATOMIC_RELAXED, __HIP_MEMORY_SCOPE_AGENT);
}
__device__ __forceinline__ ull gldll(const ull* p) {
    return __hip_atomic_load(p, __ATOMIC_RELAXED, __HIP_MEMORY_SCOPE_AGENT);
}
__device__ __forceinline__ void gstll(ull* p, ull v) {
    __hip_atomic_store(p, v, __ATOMIC_RELAXED, __HIP_MEMORY_SCOPE_AGENT);
}
__device__ __forceinline__ ull packfe(float d, int ep) {
    return ((ull)(unsigned)ep << 32) | (ull)__float_as_uint(d);
}
__device__ __forceinline__ float lowf(ull v) { return __uint_as_float((unsigned)v); }

// ---------------------------------------------------------------------------
// init: zero [hbufF(245760f) | hp1(4096) | hp2(4096) | hdec(2048)] = 256000 f
// ---------------------------------------------------------------------------
__global__ void init_k(float* __restrict__ ws) {
    for (int i = blockIdx.x * blockDim.x + threadIdx.x; i < 256000; i += gridDim.x * blockDim.x)
        ws[i] = 0.f;
}

// ---------------------------------------------------------------------------
// Encoder, ONE persistent launch, 64 steps, bf16 MFMA.
// R9: h exchange words are {epoch32 | 2xbf16}; buffer [2][15][4096] ull.
// Word j of a group buffer = int j of the LDS act2 image (identity copy).
// Producer (w, lane<16) writes 4 words; consumer batch-polls 16 words/thread.
// ---------------------------------------------------------------------------
__global__ void __launch_bounds__(256, 1) enc_all(
    const float* __restrict__ data,
    const float* __restrict__ Wih, const float* __restrict__ Whh,
    const float* __restrict__ bih, const float* __restrict__ bhh,
    ull* __restrict__ hbufF,        // [2][15][4096] {epoch|bf16x2}
    float* __restrict__ henc)       // [240][512] fp32 final h
{
    __shared__ short act2[20 * 64 * 8];
    __shared__ float gw[4][640];
    __shared__ float cs[512];
    __shared__ short hw[4][16][8];
    __shared__ float biasL[4][4][8];

    const int tid = threadIdx.x;
    const int fg = blockIdx.x >> 4, ds = blockIdx.x & 15;
    const int w = tid >> 6, lane = tid & 63;
    const int n = lane & 15, q = lane >> 4;

    short8 bfrag[2][20];
#pragma unroll
    for (int nt = 0; nt < 2; ++nt) {
        int rr = nt * 16 + n;
        int g = rr >> 3, dp = rr & 7;
        int grow = g * 512 + ds * 32 + w * 8 + dp;
#pragma unroll
        for (int kt = 0; kt < 20; ++kt) {
            int k0 = kt * 32 + q * 8;
            const float* src = (k0 < 512) ? (Whh + (size_t)grow * 512 + k0)
                                          : (Wih + (size_t)grow * 128 + (k0 - 512));
            float4 lo = *(const float4*)src;
            float4 hi = *(const float4*)(src + 4);
            short8 bf;
            bf[0] = (short)f2b(lo.x); bf[1] = (short)f2b(lo.y);
            bf[2] = (short)f2b(lo.z); bf[3] = (short)f2b(lo.w);
            bf[4] = (short)f2b(hi.x); bf[5] = (short)f2b(hi.y);
            bf[6] = (short)f2b(hi.z); bf[7] = (short)f2b(hi.w);
            bfrag[nt][kt] = bf;
        }
    }
    if (tid < 128) {
        int w2 = tid >> 5, rr = tid & 31;
        int g = rr >> 3, dp = rr & 7;
        int grow = g * 512 + ds * 32 + w2 * 8 + dp;
        biasL[w2][g][dp] = bih[grow] + bhh[grow];
    }
    for (int i = tid; i < 512; i += 256) cs[i] = 0.f;
    __syncthreads();

    unsigned* a2u = (unsigned*)act2;

    for (int t = 0; t < 64; ++t) {
        // x prefetch FIRST: global loads issue, latency hides under the h poll
        const int kt2 = tid >> 6, l2 = tid & 63, f2v = l2 & 15, q2 = l2 >> 4;
        const float* xs = data + ((size_t)t * 240 + fg * 16 + f2v) * 128 + kt2 * 32 + q2 * 8;
        float4 lo = *(const float4*)xs;
        float4 hi = *(const float4*)(xs + 4);

        // h gather: batch-poll 16 {epoch|bf16x2} words (ONE MALL window)
        {
            const ull* hsrc = hbufF + (size_t)((t & 1) * 15 + fg) * 4096;
            ull v[16];
            for (;;) {
                bool ok = true;
#pragma unroll
                for (int k2 = 0; k2 < 16; ++k2) {
                    v[k2] = gldll(hsrc + tid + 256 * k2);
                    ok &= ((int)(v[k2] >> 32) == t);
                }
                if (ok) break;
                __builtin_amdgcn_s_sleep(1);
            }
#pragma unroll
            for (int k2 = 0; k2 < 16; ++k2)
                a2u[tid + 256 * k2] = (unsigned)v[k2];
        }
        {
            short8 xp;
            xp[0] = (short)f2b(lo.x); xp[1] = (short)f2b(lo.y);
            xp[2] = (short)f2b(lo.z); xp[3] = (short)f2b(lo.w);
            xp[4] = (short)f2b(hi.x); xp[5] = (short)f2b(hi.y);
            xp[6] = (short)f2b(hi.z); xp[7] = (short)f2b(hi.w);
            *(short8*)&act2[((16 + kt2) * 64 + l2) * 8] = xp;
        }
        __syncthreads();

        floatx4 acc0 = {0.f, 0.f, 0.f, 0.f};
        floatx4 acc1 = {0.f, 0.f, 0.f, 0.f};
#pragma unroll
        for (int kt = 0; kt < 20; ++kt) {
            short8 a = *(short8*)&act2[(kt * 64 + lane) * 8];
            acc0 = __builtin_amdgcn_mfma_f32_16x16x32_bf16(a, bfrag[0][kt], acc0, 0, 0, 0);
            acc1 = __builtin_amdgcn_mfma_f32_16x16x32_bf16(a, bfrag[1][kt], acc1, 0, 0, 0);
        }
        *(floatx4*)&gw[w][(0 * 16 + n) * 20 + 4 * q] = acc0;
        *(floatx4*)&gw[w][(1 * 16 + n) * 20 + 4 * q] = acc1;

        int nb = (t + 1) & 1;
#pragma unroll
        for (int it = 0; it < 2; ++it) {
            int f = lane & 15, dp = q + 4 * it;
            float gi = gw[w][(0 * 8 + dp) * 20 + f] + biasL[w][0][dp];
            float gf = gw[w][(1 * 8 + dp) * 20 + f] + biasL[w][1][dp];
            float gg = gw[w][(2 * 8 + dp) * 20 + f] + biasL[w][2][dp];
            float go = gw[w][(3 * 8 + dp) * 20 + f] + biasL[w][3][dp];
            int ci = f * 32 + w * 8 + dp;
            float cc = cs[ci];
            float cn = sigf(gf) * cc + sigf(gi) * tanh_f(gg);
            float hn = sigf(go) * tanh_f(cn);
            cs[ci] = cn;
            hw[w][f][dp] = (short)f2b(hn);
            if (t == 63)
                gst(&henc[(size_t)(fg * 16 + f) * 512 + ds * 32 + w * 8 + dp], hn);
        }
        if (lane < 16) {
            const unsigned* hwu = (const unsigned*)&hw[w][lane][0];
            ull* dst = hbufF + (size_t)(nb * 15 + fg) * 4096 + (ds * 64 + w * 16 + lane) * 4;
            const ull ep = ((ull)(unsigned)(t + 1)) << 32;
#pragma unroll
            for (int r = 0; r < 4; ++r)
                gstll(dst + r, ep | (ull)hwu[r]);
        }
        __syncthreads();
    }
}

// ---------------------------------------------------------------------------
// xp GEMM, F/B pair fused into one launch (bid >= halfgrid -> reversed dir).
// ---------------------------------------------------------------------------
__global__ void __launch_bounds__(256) gemm_xp2(
    const float* __restrict__ A, int M, int K, int halfgrid,
    const float* __restrict__ WvF, const float* __restrict__ baF,
    const float* __restrict__ bbF, float* __restrict__ CF,
    const float* __restrict__ WvB, const float* __restrict__ baB,
    const float* __restrict__ bbB, float* __restrict__ CB)
{
    __shared__ float At[16][66];
    __shared__ float Wt[128][66];
    const int tid = threadIdx.x;
    int bgl = blockIdx.x;
    const int rev = (bgl >= halfgrid) ? 1 : 0;
    if (rev) bgl -= halfgrid;
    const float* Wv = rev ? WvB : WvF;
    const float* ba = rev ? baB : baF;
    const float* bb = rev ? bbB : bbF;
    float* C        = rev ? CB : CF;

    const int nt = bgl & 15, mt = bgl >> 4;
    const int rp = tid >> 2, fq = tid & 3;
    const int lr0 = 2 * rp, lr1 = lr0 + 1;
    const int n0 = nt * 128 + lr0, n1 = n0 + 1;

    float acc0[4], acc1[4];
    {
        float b0 = ba[n0] + bb[n0], b1 = ba[n1] + bb[n1];
#pragma unroll
        for (int j = 0; j < 4; ++j) { acc0[j] = b0; acc1[j] = b1; }
    }

    for (int kt = 0; kt < K; kt += 64) {
        {
            int f = tid >> 4, c4 = tid & 15;
            int m = mt * 16 + f;
            float4 v = make_float4(0.f, 0.f, 0.f, 0.f);
            if (m < M) {
                int ar = rev ? (M - 1 - m) : m;
                v = ((const float4*)(A + (size_t)ar * K + kt))[c4];
            }
            At[f][c4 * 4 + 0] = v.x; At[f][c4 * 4 + 1] = v.y;
            At[f][c4 * 4 + 2] = v.z; At[f][c4 * 4 + 3] = v.w;
        }
        for (int i = tid; i < 2048; i += 256) {
            int lr = i >> 4, c4 = i & 15;
            float4 v = ((const float4*)(Wv + (size_t)(nt * 128 + lr) * K + kt))[c4];
            Wt[lr][c4 * 4 + 0] = v.x; Wt[lr][c4 * 4 + 1] = v.y;
            Wt[lr][c4 * 4 + 2] = v.z; Wt[lr][c4 * 4 + 3] = v.w;
        }
        __syncthreads();
        const float2* w0p = (const float2*)(&Wt[lr0][0]);
        const float2* w1p = (const float2*)(&Wt[lr1][0]);
#pragma unroll 8
        for (int kh = 0; kh < 32; ++kh) {
            float2 w0 = w0p[kh], w1 = w1p[kh];
#pragma unroll
            for (int j = 0; j < 4; ++j) {
                float2 av = ((const float2*)(&At[4 * fq + j][0]))[kh];
                acc0[j] += w0.x * av.x + w0.y * av.y;
                acc1[j] += w1.x * av.x + w1.y * av.y;
            }
        }
        __syncthreads();
    }
#pragma unroll
    for (int j = 0; j < 4; ++j) {
        int m = mt * 16 + 4 * fq + j;
        if (m < M) {
            C[(size_t)m * 2048 + n0] = acc0[j];
            C[(size_t)m * 2048 + n1] = acc1[j];
        }
    }
}

// ---------------------------------------------------------------------------
// Pyramidal bi-LSTM (batched h poll + sleep back-off, 1 RT/step).
// ---------------------------------------------------------------------------
__global__ void __launch_bounds__(256, 1) pyr_rec(
    const float* __restrict__ xpF, const float* __restrict__ xpB,
    const float* __restrict__ WhhF, const float* __restrict__ WhhB,
    ull* __restrict__ hp,      // [dir][2][512]
    float* __restrict__ outF, float* __restrict__ outB,
    int steps)
{
    const int tid = threadIdx.x;
    const int dir = blockIdx.x >> 6, blk = blockIdx.x & 63;
    const float* xp  = dir ? xpB : xpF;
    const float* Whh = dir ? WhhB : WhhF;
    float* outp = dir ? outB : outF;
    ull* hpd = hp + (size_t)dir * 1024;

    __shared__ __align__(16) float hcur[512];
    __shared__ float red[32][9];
    __shared__ float gv[32];

    const int lr = tid & 31, seg = tid >> 5;
    const int grow = (lr >> 3) * 512 + blk * 8 + (lr & 7);
    float4 wl4[16];
#pragma unroll
    for (int j = 0; j < 16; ++j)
        wl4[j] = *(const float4*)&Whh[(size_t)grow * 512 + 4 * seg + 32 * j];

    const int growx = (tid >> 3) * 512 + blk * 8 + (tid & 7);   // for tid<32
    float creg = 0.f;
    __syncthreads();

    for (int t = 0; t < steps; ++t) {
        float xg = 0.f;
        if (tid < 32) xg = xp[(size_t)t * 2048 + growx];   // prefetch (no h dep)
        {
            const ull* base = hpd + (size_t)(t & 1) * 512;
            ull v0 = gldll(base + tid), v1 = gldll(base + tid + 256);
            while (((int)(v0 >> 32) != t) | ((int)(v1 >> 32) != t)) {
                __builtin_amdgcn_s_sleep(1);
                v0 = gldll(base + tid);
                v1 = gldll(base + tid + 256);
            }
            hcur[tid]       = lowf(v0);
            hcur[tid + 256] = lowf(v1);
        }
        __syncthreads();

        float a = 0.f;
#pragma unroll
        for (int j = 0; j < 16; ++j) {
            float4 w = wl4[j];
            float4 h4 = *(const float4*)&hcur[4 * seg + 32 * j];
            a += w.x*h4.x + w.y*h4.y + w.z*h4.z + w.w*h4.w;
        }
        red[lr][seg] = a;
        __syncthreads();

        if (tid < 32) {
            float g = xg;
#pragma unroll
            for (int s2 = 0; s2 < 8; ++s2) g += red[tid][s2];
            gv[tid] = g;
        }
        __syncthreads();
        if (tid < 8) {
            float i_ = sigf(gv[tid]), f_ = sigf(gv[8 + tid]);
            float g_ = tanh_f(gv[16 + tid]), o_ = sigf(gv[24 + tid]);
            creg = f_ * creg + i_ * g_;
            float hn = o_ * tanh_f(creg);
            int d = blk * 8 + tid;
            gstll(&hpd[((t + 1) & 1) * 512 + d], packfe(hn, t + 1));
            int row = dir ? (steps - 1 - t) : t;
            outp[(size_t)row * 512 + d] = hn;
        }
        __syncthreads();
    }
}

__global__ void x2_assemble(const float* __restrict__ f1, const float* __restrict__ b1o,
                            float* __restrict__ x2)
{
    int j = blockIdx.x;
    for (int k = threadIdx.x; k < 2048; k += 256) {
        int q = k >> 9, r = k & 511;
        const float* src = (q & 1) ? b1o : f1;
        int row = 2 * j + (q >> 1);
        x2[(size_t)j * 2048 + k] = src[(size_t)row * 512 + r];
    }
}

// ctx assemble + publish hdec slot 0 with epoch 0
__global__ void ctx_k(const float* __restrict__ f2, const float* __restrict__ b2o,
                      float* __restrict__ ctx, ull* __restrict__ hdec_p)
{
    int j = blockIdx.x;
    for (int k = threadIdx.x; k < 1024; k += 256)
        ctx[(size_t)j * 1024 + k] = (k < 512) ? f2[(size_t)j * 512 + k]
                                              : b2o[(size_t)j * 512 + k - 512];
    if (j == 0) {
        for (int i = threadIdx.x; i < 512; i += 256)
            hdec_p[i] = packfe(f2[59 * 512 + i], 0);
    }
}

// ---------------------------------------------------------------------------
// precompute M = comb_W[:, 8:1032] @ ctx^T  -> Mg[512][60]
// ---------------------------------------------------------------------------
__global__ void __launch_bounds__(256) precomp_M(
    const float* __restrict__ comb_W,   // [512][1032]
    const float* __restrict__ ctx,      // [60][1024]
    float* __restrict__ Mg)             // [512][60]
{
    __shared__ float cw[8 * 1024];      // 32 KB: comb_W rows d0..d0+8, cols 8..1032
    const int tid = threadIdx.x, d0 = blockIdx.x * 8;
    for (int i = tid; i < 2048; i += 256) {
        int r = i >> 8, c4 = i & 255;
        float4 v = *(const float4*)&comb_W[(size_t)(d0 + r) * 1032 + 8 + 4 * c4];
        *(float4*)&cw[r * 1024 + 4 * c4] = v;
    }
    __syncthreads();
    for (int o = tid; o < 480; o += 256) {
        int dl = o / 60, j = o % 60;
        const float4* cp = (const float4*)&cw[dl * 1024];
        const float4* xp = (const float4*)(ctx + (size_t)j * 1024);
        float a = 0.f;
#pragma unroll 4
        for (int k = 0; k < 256; ++k) {
            float4 w = cp[k], x = xp[k];
            a += w.x * x.x + w.y * x.y + w.z * x.z + w.w * x.w;
        }
        Mg[(size_t)(d0 + dl) * 60 + j] = a;
    }
}

// ---------------------------------------------------------------------------
// Decoder: 64 identical blocks, 8 h-dims each; only cross-block payload per
// step is the h all-to-all (1 MALL RT/step). Parity double-buffered h with
// exact-epoch words (mutual-gating safety).
// ---------------------------------------------------------------------------
__global__ void __launch_bounds__(256, 1) dec_k(
    const float* __restrict__ attn_W, const float* __restrict__ attn_b,
    const float* __restrict__ comb_W, const float* __restrict__ comb_b,
    const float* __restrict__ gWih, const float* __restrict__ gWhh,
    const float* __restrict__ gbih, const float* __restrict__ gbhh,
    const float* __restrict__ outW, const float* __restrict__ outb,
    const float* __restrict__ Mg,   // [512][60]
    ull* __restrict__ hdec_p,       // [2][512]
    float* __restrict__ dout)
{
    const int tid = threadIdx.x, bid = blockIdx.x;   // 64 blocks
    const int dbase = bid * 8;

    __shared__ float M2[512][70];                    // cols: [M(60) | Minp(8) | pad2]
    __shared__ __align__(16) float hx[528];          // [inpl(8); h(512); pad0(8)]
    __shared__ __align__(16) float xl[512];          // o
    __shared__ __align__(8) float awx[68];           // [aw(60); inp(8)]
    __shared__ float redA[64][5];
    __shared__ float redGH[32][9];
    __shared__ float redG[32][9];
    __shared__ float redO[8][33];
    __shared__ float biasg[24], biasi[24];
    __shared__ float cbL[512];
    __shared__ float attnbL[64];

    float4 wa4[33], wo4[4], wg4[16], wi4[16];
    const int rz = tid >> 2, sz = tid & 3;  // z: 60(64) rows x 4 segs
    const int ro = tid >> 5, so = tid & 31; // logits: 8 rows x 32 segs
    const int rg = tid >> 3, sg = tid & 7;  // gh/gi: 24(32) rows x 8 segs

    // ---- weights to registers (every block holds ALL roles) ----
    {
        int rr = (rz < 60) ? rz : 59;
#pragma unroll
        for (int i = 0; i < 32; ++i)
            wa4[i] = *(const float4*)&attn_W[(size_t)rr * 520 + 4 * sz + 16 * i];
        float* wap = (float*)&wa4[32];
#pragma unroll
        for (int r = 0; r < 4; ++r) {
            int k = 4 * sz + 512 + r;
            wap[r] = (k < 520) ? attn_W[(size_t)rr * 520 + k] : 0.f;
        }
    }
#pragma unroll
    for (int i = 0; i < 4; ++i)
        wo4[i] = *(const float4*)&outW[(size_t)ro * 512 + 4 * so + 128 * i];
    {
        int rr = (rg < 24) ? rg : 23;
        int grow = (rr >> 3) * 512 + dbase + (rr & 7);
#pragma unroll
        for (int j = 0; j < 16; ++j) {
            wg4[j] = *(const float4*)&gWhh[(size_t)grow * 512 + 4 * sg + 32 * j];
            wi4[j] = *(const float4*)&gWih[(size_t)grow * 512 + 4 * sg + 32 * j];
        }
    }
    if (tid < 24) {
        int g2 = (tid >> 3) * 512 + dbase + (tid & 7);
        biasg[tid] = gbhh[g2];
        biasi[tid] = gbih[g2];
    }
    for (int i = tid; i < 512; i += 256) cbL[i] = comb_b[i];
    if (tid < 64) attnbL[tid] = (tid < 60) ? attn_b[tid] : 0.f;
    if (tid < 8) hx[520 + tid] = 0.f;
    // M2 load: cols 0..59 from Mg, cols 60..67 = comb_W[:,0..8)
    for (int i = tid; i < 512 * 15; i += 256) {
        int r = i / 15, c4 = i % 15;
        float4 v = *(const float4*)&Mg[(size_t)r * 60 + 4 * c4];
        M2[r][4 * c4 + 0] = v.x; M2[r][4 * c4 + 1] = v.y;
        M2[r][4 * c4 + 2] = v.z; M2[r][4 * c4 + 3] = v.w;
    }
    for (int i = tid; i < 512 * 2; i += 256) {
        int r = i >> 1, h4 = i & 1;
        float4 v = *(const float4*)&comb_W[(size_t)r * 1032 + 4 * h4];
        M2[r][60 + 4 * h4 + 0] = v.x; M2[r][60 + 4 * h4 + 1] = v.y;
        M2[r][60 + 4 * h4 + 2] = v.z; M2[r][60 + 4 * h4 + 3] = v.w;
    }
    __syncthreads();

    for (int s = 0; s < 30; ++s) {
        // ---- the ONE cross-block hop: h (slot s&1, epoch s), batched poll ----
        {
            const ull* hs = hdec_p + (size_t)(s & 1) * 512;
            ull v0 = gldll(hs + tid), v1 = gldll(hs + tid + 256);
            while (((int)(v0 >> 32) != s) | ((int)(v1 >> 32) != s)) {
                __builtin_amdgcn_s_sleep(1);
                v0 = gldll(hs + tid);
                v1 = gldll(hs + tid + 256);
            }
            hx[8 + tid]       = lowf(v0);
            hx[8 + tid + 256] = lowf(v1);
        }
        __syncthreads();

        // phase A: logits partial (s>0) + gh partial (both need only h)
        if (s > 0) {
            float a = 0.f;
#pragma unroll
            for (int i = 0; i < 4; ++i) {
                float4 w = wo4[i];
                float4 h4 = *(const float4*)&hx[8 + 4 * so + 128 * i];
                a += w.x*h4.x + w.y*h4.y + w.z*h4.z + w.w*h4.w;
            }
            redO[ro][so] = a;
        }
        {
            float a = 0.f;
#pragma unroll
            for (int j = 0; j < 16; ++j) {
                float4 w = wg4[j];
                float4 h4 = *(const float4*)&hx[8 + 4 * sg + 32 * j];
                a += w.x*h4.x + w.y*h4.y + w.z*h4.z + w.w*h4.w;
            }
            redGH[rg][sg] = a;
        }
        __syncthreads();

        // phase B: inp = log_softmax(outW@h) (or one-hot at s=0), lanes 0..7
        if (tid < 8) {
            float v;
            if (s > 0) {
                float a = outb[tid];
#pragma unroll
                for (int g2 = 0; g2 < 32; ++g2) a += redO[tid][g2];
                float m = a;
                m = fmaxf(m, __shfl_xor(m, 1));
                m = fmaxf(m, __shfl_xor(m, 2));
                m = fmaxf(m, __shfl_xor(m, 4));
                float e = __expf(a - m);
                float ss2 = e;
                ss2 += __shfl_xor(ss2, 1);
                ss2 += __shfl_xor(ss2, 2);
                ss2 += __shfl_xor(ss2, 4);
                v = a - m - __logf(ss2);
                if (bid == 0) dout[(s - 1) * 8 + tid] = v;
            } else {
                v = (tid == 7) ? 1.f : 0.f;
            }
            hx[tid] = v;
            awx[60 + tid] = v;
        }
        __syncthreads();

        // phase C: z partial = attn_W @ [inp; h]
        {
            float a = 0.f;
#pragma unroll
            for (int i = 0; i < 33; ++i) {
                float4 w = wa4[i];
                float4 x4 = *(const float4*)&hx[4 * sz + 16 * i];
                a += w.x*x4.x + w.y*x4.y + w.z*x4.z + w.w*x4.w;
            }
            redA[rz][sz] = a;
        }
        __syncthreads();

        // phase D: wave-0 parallel 60-wide softmax -> awx[0..60)
        if (tid < 64) {
            float z = -1e30f;
            if (tid < 60)
                z = attnbL[tid] + redA[tid][0] + redA[tid][1] + redA[tid][2] + redA[tid][3];
            float m = z;
#pragma unroll
            for (int off = 32; off; off >>= 1) m = fmaxf(m, __shfl_xor(m, off));
            float e = (tid < 60) ? __expf(z - m) : 0.f;
            float ss2 = e;
#pragma unroll
            for (int off = 32; off; off >>= 1) ss2 += __shfl_xor(ss2, off);
            if (tid < 60) awx[tid] = e / ss2;
        }
        __syncthreads();

        // phase E: o = relu(M2 @ [aw; inp] + comb_b), 2 dims/thread
#pragma unroll
        for (int half = 0; half < 2; ++half) {
            int c = tid + half * 256;
            float a = cbL[c];
            const float2* mrow = (const float2*)&M2[c][0];
            const float2* xv = (const float2*)&awx[0];
#pragma unroll
            for (int jj = 0; jj < 34; ++jj) {
                float2 mm = mrow[jj], xx = xv[jj];
                a += mm.x * xx.x + mm.y * xx.y;
            }
            xl[c] = fmaxf(a, 0.f);
        }
        __syncthreads();

        // phase F: gi partial = gWih @ o
        {
            float a = 0.f;
#pragma unroll
            for (int j = 0; j < 16; ++j) {
                float4 w = wi4[j];
                float4 o4 = *(const float4*)&xl[4 * sg + 32 * j];
                a += w.x*o4.x + w.y*o4.y + w.z*o4.z + w.w*o4.w;
            }
            redG[rg][sg] = a;
        }
        __syncthreads();

        // phase G: reduce + GRU combine + publish (8 threads, 3 gate rows each)
        if (tid < 8) {
            float gh0 = biasg[tid], gh1 = biasg[8 + tid], gh2 = biasg[16 + tid];
            float gi0 = biasi[tid], gi1 = biasi[8 + tid], gi2 = biasi[16 + tid];
#pragma unroll
            for (int g2 = 0; g2 < 8; ++g2) {
                gh0 += redGH[tid][g2]; gh1 += redGH[8 + tid][g2]; gh2 += redGH[16 + tid][g2];
                gi0 += redG[tid][g2];  gi1 += redG[8 + tid][g2];  gi2 += redG[16 + tid][g2];
            }
            float r_ = sigf(gi0 + gh0);
            float z_ = sigf(gi1 + gh1);
            float n_ = tanh_f(gi2 + r_ * gh2);
            float hnew = (1.f - z_) * n_ + z_ * hx[8 + dbase + tid];
            gstll(&hdec_p[(size_t)((s + 1) & 1) * 512 + dbase + tid], packfe(hnew, s + 1));
        }
        __syncthreads();   // protect hx/awx/xl before next-step overwrite
    }

    // epilogue: logits for s=29 (block 0 only)
    if (bid == 0) {
        {
            const ull* hs = hdec_p + (size_t)(30 & 1) * 512;
            ull v0 = gldll(hs + tid), v1 = gldll(hs + tid + 256);
            while (((int)(v0 >> 32) != 30) | ((int)(v1 >> 32) != 30)) {
                __builtin_amdgcn_s_sleep(1);
                v0 = gldll(hs + tid);
                v1 = gldll(hs + tid + 256);
            }
            hx[8 + tid]       = lowf(v0);
            hx[8 + tid + 256] = lowf(v1);
        }
        __syncthreads();
        {
            float a = 0.f;
#pragma unroll
            for (int i = 0; i < 4; ++i) {
                float4 w = wo4[i];
                float4 h4 = *(const float4*)&hx[8 + 4 * so + 128 * i];
                a += w.x*h4.x + w.y*h4.y + w.z*h4.z + w.w*h4.w;
            }
            redO[ro][so] = a;
        }
        __syncthreads();
        if (tid < 8) {
            float a = outb[tid];
#pragma unroll
            for (int g2 = 0; g2 < 32; ++g2) a += redO[tid][g2];
            float m = a;
            m = fmaxf(m, __shfl_xor(m, 1));
            m = fmaxf(m, __shfl_xor(m, 2));
            m = fmaxf(m, __shfl_xor(m, 4));
            float e = __expf(a - m);
            float ss2 = e;
            ss2 += __shfl_xor(ss2, 1);
            ss2 += __shfl_xor(ss2, 2);
            ss2 += __shfl_xor(ss2, 4);
            dout[29 * 8 + tid] = a - m - __logf(ss2);
        }
    }
}

// ---------------------------------------------------------------------------
extern "C" void kernel_launch(void* const* d_in, const int* in_sizes, int n_in,
                              void* d_out, int out_size, void* d_ws, size_t ws_size,
                              hipStream_t stream) {
    (void)in_sizes; (void)n_in; (void)out_size; (void)ws_size;
    const float* data    = (const float*)d_in[0];
    const float* enc_Wih = (const float*)d_in[1];
    const float* enc_Whh = (const float*)d_in[2];
    const float* enc_bih = (const float*)d_in[3];
    const float* enc_bhh = (const float*)d_in[4];
    const float* p1f_Wih = (const float*)d_in[5];
    const float* p1f_Whh = (const float*)d_in[6];
    const float* p1f_bih = (const float*)d_in[7];
    const float* p1f_bhh = (const float*)d_in[8];
    const float* p1b_Wih = (const float*)d_in[9];
    const float* p1b_Whh = (const float*)d_in[10];
    const float* p1b_bih = (const float*)d_in[11];
    const float* p1b_bhh = (const float*)d_in[12];
    const float* p2f_Wih = (const float*)d_in[13];
    const float* p2f_Whh = (const float*)d_in[14];
    const float* p2f_bih = (const float*)d_in[15];
    const float* p2f_bhh = (const float*)d_in[16];
    const float* p2b_Wih = (const float*)d_in[17];
    const float* p2b_Whh = (const float*)d_in[18];
    const float* p2b_bih = (const float*)d_in[19];
    const float* p2b_bhh = (const float*)d_in[20];
    const float* attn_W  = (const float*)d_in[21];
    const float* attn_b  = (const float*)d_in[22];
    const float* comb_W  = (const float*)d_in[23];
    const float* comb_b  = (const float*)d_in[24];
    const float* gru_Wih = (const float*)d_in[25];
    const float* gru_Whh = (const float*)d_in[26];
    const float* gru_bih = (const float*)d_in[27];
    const float* gru_bhh = (const float*)d_in[28];
    const float* out_W   = (const float*)d_in[29];
    const float* out_b   = (const float*)d_in[30];

    float* ws = (float*)d_ws;
    // zeroed region [0 .. 256000)
    ull* hbufF   = (ull*)ws;                 // 245760 floats = [2][15][4096] ull
    ull* hp1     = (ull*)(ws + 245760);      // 4096 floats = [2][2][512] ull
    ull* hp2     = (ull*)(ws + 249856);      // 4096 floats
    ull* hdec_p  = (ull*)(ws + 253952);      // 2048 floats = [2][512] ull -> end 256000
    // non-zeroed scratch
    float* henc  = ws + 256000;              // 122880
    float* xp1f  = ws + 378880;              // 245760
    float* xp1b  = ws + 624640;              // 245760
    float* f1    = ws + 870400;              // 61440
    float* b1o   = ws + 931840;              // 61440
    float* x2    = ws + 993280;              // 122880
    float* xp2f  = ws + 1116160;             // 122880
    float* xp2b  = ws + 1239040;             // 122880
    float* f2    = ws + 1361920;             // 30720
    float* b2o   = ws + 1392640;             // 30720
    float* ctxb  = ws + 1423360;             // 61440
    float* Mg    = ws + 1484800;             // 30720 -> end 1515520

    init_k<<<256, 256, 0, stream>>>(ws);

    enc_all<<<240, 256, 0, stream>>>(data, enc_Wih, enc_Whh, enc_bih, enc_bhh,
                                     hbufF, henc);
    gemm_xp2<<<256, 256, 0, stream>>>(henc, 120, 1024, 128,
                                      p1f_Wih, p1f_bih, p1f_bhh, xp1f,
                                      p1b_Wih, p1b_bih, p1b_bhh, xp1b);
    pyr_rec<<<128, 256, 0, stream>>>(xp1f, xp1b, p1f_Whh, p1b_Whh, hp1, f1, b1o, 120);
    x2_assemble<<<60, 256, 0, stream>>>(f1, b1o, x2);
    gemm_xp2<<<128, 256, 0, stream>>>(x2, 60, 2048, 64,
                                      p2f_Wih, p2f_bih, p2f_bhh, xp2f,
                                      p2b_Wih, p2b_bih, p2b_bhh, xp2b);
    pyr_rec<<<128, 256, 0, stream>>>(xp2f, xp2b, p2f_Whh, p2b_Whh, hp2, f2, b2o, 60);
    ctx_k<<<60, 256, 0, stream>>>(f2, b2o, ctxb, hdec_p);
    precomp_M<<<64, 256, 0, stream>>>(comb_W, ctxb, Mg);
    dec_k<<<64, 256, 0, stream>>>(attn_W, attn_b, comb_W, comb_b,
                                  gru_Wih, gru_Whh, gru_bih, gru_bhh,
                                  out_W, out_b, Mg, hdec_p,
                                  (float*)d_out);
}

// Round 5
// 1291.235 us; speedup vs baseline: 1.4407x; 1.0211x over previous
//
#include <hip/hip_runtime.h>
#include <math.h>

// Model dims: H=512 D=128 L=8 T=64 W=240 CTX=60 NSTEPS=30

typedef __attribute__((ext_vector_type(8))) short short8;
typedef __attribute__((ext_vector_type(4))) float floatx4;
typedef unsigned long long ull;

__device__ __forceinline__ float sigf(float x) { return 1.f / (1.f + __expf(-x)); }
__device__ __forceinline__ float tanh_f(float x) {
    float e = __expf(2.f * x);
    return 1.f - 2.f / (e + 1.f);
}
__device__ __forceinline__ unsigned short f2b(float x) {   // fp32 -> bf16 RNE
    unsigned u = __float_as_uint(x);
    unsigned r = (u + 0x7FFFu + ((u >> 16) & 1u)) >> 16;
    return (unsigned short)r;
}

// RELAXED agent-scope atomics only (acquire/release emit buffer_inv/wbl2 on
// gfx950 and trash the XCD L2). Cross-block payloads are {epoch|data} ull
// words polled directly (data+readiness in one MALL round trip), batch-polled.
// R10: dec_k moves to 512 threads + shuffle-tree reductions. The R8/R9 dec_k
// held 276 floats of weights/thread against 228 allocated VGPRs -> spill
// reloads on every step's serial chain; 512 threads cut per-thread weights to
// ~144 floats (no spill) and shuffle reductions shorten the chain (6 barriers,
// no serial 32/48-element LDS sum loops).
__device__ __forceinline__ float gld(const float* p) {
    return __hip_atomic_load(p, __ATOMIC_RELAXED, __HIP_MEMORY_SCOPE_AGENT);
}
__device__ __forceinline__ void gst(float* p, float v) {
    __hip_atomic_store(p, v, __ATOMIC_RELAXED, __HIP_MEMORY_SCOPE_AGENT);
}
__device__ __forceinline__ ull gldll(const ull* p) {
    return __hip_atomic_load(p, __ATOMIC_RELAXED, __HIP_MEMORY_SCOPE_AGENT);
}
__device__ __forceinline__ void gstll(ull* p, ull v) {
    __hip_atomic_store(p, v, __ATOMIC_RELAXED, __HIP_MEMORY_SCOPE_AGENT);
}
__device__ __forceinline__ ull packfe(float d, int ep) {
    return ((ull)(unsigned)ep << 32) | (ull)__float_as_uint(d);
}
__device__ __forceinline__ float lowf(ull v) { return __uint_as_float((unsigned)v); }

// ---------------------------------------------------------------------------
// init: zero [hbufF(245760f) | hp1(4096) | hp2(4096) | hdec(2048)] = 256000 f
// ---------------------------------------------------------------------------
__global__ void init_k(float* __restrict__ ws) {
    for (int i = blockIdx.x * blockDim.x + threadIdx.x; i < 256000; i += gridDim.x * blockDim.x)
        ws[i] = 0.f;
}

// ---------------------------------------------------------------------------
// Encoder, ONE persistent launch, 64 steps, bf16 MFMA (unchanged from R9).
// ---------------------------------------------------------------------------
__global__ void __launch_bounds__(256, 1) enc_all(
    const float* __restrict__ data,
    const float* __restrict__ Wih, const float* __restrict__ Whh,
    const float* __restrict__ bih, const float* __restrict__ bhh,
    ull* __restrict__ hbufF,        // [2][15][4096] {epoch|bf16x2}
    float* __restrict__ henc)       // [240][512] fp32 final h
{
    __shared__ short act2[20 * 64 * 8];
    __shared__ float gw[4][640];
    __shared__ float cs[512];
    __shared__ short hw[4][16][8];
    __shared__ float biasL[4][4][8];

    const int tid = threadIdx.x;
    const int fg = blockIdx.x >> 4, ds = blockIdx.x & 15;
    const int w = tid >> 6, lane = tid & 63;
    const int n = lane & 15, q = lane >> 4;

    short8 bfrag[2][20];
#pragma unroll
    for (int nt = 0; nt < 2; ++nt) {
        int rr = nt * 16 + n;
        int g = rr >> 3, dp = rr & 7;
        int grow = g * 512 + ds * 32 + w * 8 + dp;
#pragma unroll
        for (int kt = 0; kt < 20; ++kt) {
            int k0 = kt * 32 + q * 8;
            const float* src = (k0 < 512) ? (Whh + (size_t)grow * 512 + k0)
                                          : (Wih + (size_t)grow * 128 + (k0 - 512));
            float4 lo = *(const float4*)src;
            float4 hi = *(const float4*)(src + 4);
            short8 bf;
            bf[0] = (short)f2b(lo.x); bf[1] = (short)f2b(lo.y);
            bf[2] = (short)f2b(lo.z); bf[3] = (short)f2b(lo.w);
            bf[4] = (short)f2b(hi.x); bf[5] = (short)f2b(hi.y);
            bf[6] = (short)f2b(hi.z); bf[7] = (short)f2b(hi.w);
            bfrag[nt][kt] = bf;
        }
    }
    if (tid < 128) {
        int w2 = tid >> 5, rr = tid & 31;
        int g = rr >> 3, dp = rr & 7;
        int grow = g * 512 + ds * 32 + w2 * 8 + dp;
        biasL[w2][g][dp] = bih[grow] + bhh[grow];
    }
    for (int i = tid; i < 512; i += 256) cs[i] = 0.f;
    __syncthreads();

    unsigned* a2u = (unsigned*)act2;

    for (int t = 0; t < 64; ++t) {
        // x prefetch FIRST: global loads issue, latency hides under the h poll
        const int kt2 = tid >> 6, l2 = tid & 63, f2v = l2 & 15, q2 = l2 >> 4;
        const float* xs = data + ((size_t)t * 240 + fg * 16 + f2v) * 128 + kt2 * 32 + q2 * 8;
        float4 lo = *(const float4*)xs;
        float4 hi = *(const float4*)(xs + 4);

        // h gather: batch-poll 16 {epoch|bf16x2} words (ONE MALL window)
        {
            const ull* hsrc = hbufF + (size_t)((t & 1) * 15 + fg) * 4096;
            ull v[16];
            for (;;) {
                bool ok = true;
#pragma unroll
                for (int k2 = 0; k2 < 16; ++k2) {
                    v[k2] = gldll(hsrc + tid + 256 * k2);
                    ok &= ((int)(v[k2] >> 32) == t);
                }
                if (ok) break;
                __builtin_amdgcn_s_sleep(1);
            }
#pragma unroll
            for (int k2 = 0; k2 < 16; ++k2)
                a2u[tid + 256 * k2] = (unsigned)v[k2];
        }
        {
            short8 xp;
            xp[0] = (short)f2b(lo.x); xp[1] = (short)f2b(lo.y);
            xp[2] = (short)f2b(lo.z); xp[3] = (short)f2b(lo.w);
            xp[4] = (short)f2b(hi.x); xp[5] = (short)f2b(hi.y);
            xp[6] = (short)f2b(hi.z); xp[7] = (short)f2b(hi.w);
            *(short8*)&act2[((16 + kt2) * 64 + l2) * 8] = xp;
        }
        __syncthreads();

        floatx4 acc0 = {0.f, 0.f, 0.f, 0.f};
        floatx4 acc1 = {0.f, 0.f, 0.f, 0.f};
#pragma unroll
        for (int kt = 0; kt < 20; ++kt) {
            short8 a = *(short8*)&act2[(kt * 64 + lane) * 8];
            acc0 = __builtin_amdgcn_mfma_f32_16x16x32_bf16(a, bfrag[0][kt], acc0, 0, 0, 0);
            acc1 = __builtin_amdgcn_mfma_f32_16x16x32_bf16(a, bfrag[1][kt], acc1, 0, 0, 0);
        }
        *(floatx4*)&gw[w][(0 * 16 + n) * 20 + 4 * q] = acc0;
        *(floatx4*)&gw[w][(1 * 16 + n) * 20 + 4 * q] = acc1;

        int nb = (t + 1) & 1;
#pragma unroll
        for (int it = 0; it < 2; ++it) {
            int f = lane & 15, dp = q + 4 * it;
            float gi = gw[w][(0 * 8 + dp) * 20 + f] + biasL[w][0][dp];
            float gf = gw[w][(1 * 8 + dp) * 20 + f] + biasL[w][1][dp];
            float gg = gw[w][(2 * 8 + dp) * 20 + f] + biasL[w][2][dp];
            float go = gw[w][(3 * 8 + dp) * 20 + f] + biasL[w][3][dp];
            int ci = f * 32 + w * 8 + dp;
            float cc = cs[ci];
            float cn = sigf(gf) * cc + sigf(gi) * tanh_f(gg);
            float hn = sigf(go) * tanh_f(cn);
            cs[ci] = cn;
            hw[w][f][dp] = (short)f2b(hn);
            if (t == 63)
                gst(&henc[(size_t)(fg * 16 + f) * 512 + ds * 32 + w * 8 + dp], hn);
        }
        if (lane < 16) {
            const unsigned* hwu = (const unsigned*)&hw[w][lane][0];
            ull* dst = hbufF + (size_t)(nb * 15 + fg) * 4096 + (ds * 64 + w * 16 + lane) * 4;
            const ull ep = ((ull)(unsigned)(t + 1)) << 32;
#pragma unroll
            for (int r = 0; r < 4; ++r)
                gstll(dst + r, ep | (ull)hwu[r]);
        }
        __syncthreads();
    }
}

// ---------------------------------------------------------------------------
// xp GEMM, F/B pair fused into one launch (unchanged).
// ---------------------------------------------------------------------------
__global__ void __launch_bounds__(256) gemm_xp2(
    const float* __restrict__ A, int M, int K, int halfgrid,
    const float* __restrict__ WvF, const float* __restrict__ baF,
    const float* __restrict__ bbF, float* __restrict__ CF,
    const float* __restrict__ WvB, const float* __restrict__ baB,
    const float* __restrict__ bbB, float* __restrict__ CB)
{
    __shared__ float At[16][66];
    __shared__ float Wt[128][66];
    const int tid = threadIdx.x;
    int bgl = blockIdx.x;
    const int rev = (bgl >= halfgrid) ? 1 : 0;
    if (rev) bgl -= halfgrid;
    const float* Wv = rev ? WvB : WvF;
    const float* ba = rev ? baB : baF;
    const float* bb = rev ? bbB : bbF;
    float* C        = rev ? CB : CF;

    const int nt = bgl & 15, mt = bgl >> 4;
    const int rp = tid >> 2, fq = tid & 3;
    const int lr0 = 2 * rp, lr1 = lr0 + 1;
    const int n0 = nt * 128 + lr0, n1 = n0 + 1;

    float acc0[4], acc1[4];
    {
        float b0 = ba[n0] + bb[n0], b1 = ba[n1] + bb[n1];
#pragma unroll
        for (int j = 0; j < 4; ++j) { acc0[j] = b0; acc1[j] = b1; }
    }

    for (int kt = 0; kt < K; kt += 64) {
        {
            int f = tid >> 4, c4 = tid & 15;
            int m = mt * 16 + f;
            float4 v = make_float4(0.f, 0.f, 0.f, 0.f);
            if (m < M) {
                int ar = rev ? (M - 1 - m) : m;
                v = ((const float4*)(A + (size_t)ar * K + kt))[c4];
            }
            At[f][c4 * 4 + 0] = v.x; At[f][c4 * 4 + 1] = v.y;
            At[f][c4 * 4 + 2] = v.z; At[f][c4 * 4 + 3] = v.w;
        }
        for (int i = tid; i < 2048; i += 256) {
            int lr = i >> 4, c4 = i & 15;
            float4 v = ((const float4*)(Wv + (size_t)(nt * 128 + lr) * K + kt))[c4];
            Wt[lr][c4 * 4 + 0] = v.x; Wt[lr][c4 * 4 + 1] = v.y;
            Wt[lr][c4 * 4 + 2] = v.z; Wt[lr][c4 * 4 + 3] = v.w;
        }
        __syncthreads();
        const float2* w0p = (const float2*)(&Wt[lr0][0]);
        const float2* w1p = (const float2*)(&Wt[lr1][0]);
#pragma unroll 8
        for (int kh = 0; kh < 32; ++kh) {
            float2 w0 = w0p[kh], w1 = w1p[kh];
#pragma unroll
            for (int j = 0; j < 4; ++j) {
                float2 av = ((const float2*)(&At[4 * fq + j][0]))[kh];
                acc0[j] += w0.x * av.x + w0.y * av.y;
                acc1[j] += w1.x * av.x + w1.y * av.y;
            }
        }
        __syncthreads();
    }
#pragma unroll
    for (int j = 0; j < 4; ++j) {
        int m = mt * 16 + 4 * fq + j;
        if (m < M) {
            C[(size_t)m * 2048 + n0] = acc0[j];
            C[(size_t)m * 2048 + n1] = acc1[j];
        }
    }
}

// ---------------------------------------------------------------------------
// Pyramidal bi-LSTM (unchanged).
// ---------------------------------------------------------------------------
__global__ void __launch_bounds__(256, 1) pyr_rec(
    const float* __restrict__ xpF, const float* __restrict__ xpB,
    const float* __restrict__ WhhF, const float* __restrict__ WhhB,
    ull* __restrict__ hp,      // [dir][2][512]
    float* __restrict__ outF, float* __restrict__ outB,
    int steps)
{
    const int tid = threadIdx.x;
    const int dir = blockIdx.x >> 6, blk = blockIdx.x & 63;
    const float* xp  = dir ? xpB : xpF;
    const float* Whh = dir ? WhhB : WhhF;
    float* outp = dir ? outB : outF;
    ull* hpd = hp + (size_t)dir * 1024;

    __shared__ __align__(16) float hcur[512];
    __shared__ float red[32][9];
    __shared__ float gv[32];

    const int lr = tid & 31, seg = tid >> 5;
    const int grow = (lr >> 3) * 512 + blk * 8 + (lr & 7);
    float4 wl4[16];
#pragma unroll
    for (int j = 0; j < 16; ++j)
        wl4[j] = *(const float4*)&Whh[(size_t)grow * 512 + 4 * seg + 32 * j];

    const int growx = (tid >> 3) * 512 + blk * 8 + (tid & 7);   // for tid<32
    float creg = 0.f;
    __syncthreads();

    for (int t = 0; t < steps; ++t) {
        float xg = 0.f;
        if (tid < 32) xg = xp[(size_t)t * 2048 + growx];   // prefetch (no h dep)
        {
            const ull* base = hpd + (size_t)(t & 1) * 512;
            ull v0 = gldll(base + tid), v1 = gldll(base + tid + 256);
            while (((int)(v0 >> 32) != t) | ((int)(v1 >> 32) != t)) {
                __builtin_amdgcn_s_sleep(1);
                v0 = gldll(base + tid);
                v1 = gldll(base + tid + 256);
            }
            hcur[tid]       = lowf(v0);
            hcur[tid + 256] = lowf(v1);
        }
        __syncthreads();

        float a = 0.f;
#pragma unroll
        for (int j = 0; j < 16; ++j) {
            float4 w = wl4[j];
            float4 h4 = *(const float4*)&hcur[4 * seg + 32 * j];
            a += w.x*h4.x + w.y*h4.y + w.z*h4.z + w.w*h4.w;
        }
        red[lr][seg] = a;
        __syncthreads();

        if (tid < 32) {
            float g = xg;
#pragma unroll
            for (int s2 = 0; s2 < 8; ++s2) g += red[tid][s2];
            gv[tid] = g;
        }
        __syncthreads();
        if (tid < 8) {
            float i_ = sigf(gv[tid]), f_ = sigf(gv[8 + tid]);
            float g_ = tanh_f(gv[16 + tid]), o_ = sigf(gv[24 + tid]);
            creg = f_ * creg + i_ * g_;
            float hn = o_ * tanh_f(creg);
            int d = blk * 8 + tid;
            gstll(&hpd[((t + 1) & 1) * 512 + d], packfe(hn, t + 1));
            int row = dir ? (steps - 1 - t) : t;
            outp[(size_t)row * 512 + d] = hn;
        }
        __syncthreads();
    }
}

__global__ void x2_assemble(const float* __restrict__ f1, const float* __restrict__ b1o,
                            float* __restrict__ x2)
{
    int j = blockIdx.x;
    for (int k = threadIdx.x; k < 2048; k += 256) {
        int q = k >> 9, r = k & 511;
        const float* src = (q & 1) ? b1o : f1;
        int row = 2 * j + (q >> 1);
        x2[(size_t)j * 2048 + k] = src[(size_t)row * 512 + r];
    }
}

// ctx assemble + publish hdec slot 0 with epoch 0
__global__ void ctx_k(const float* __restrict__ f2, const float* __restrict__ b2o,
                      float* __restrict__ ctx, ull* __restrict__ hdec_p)
{
    int j = blockIdx.x;
    for (int k = threadIdx.x; k < 1024; k += 256)
        ctx[(size_t)j * 1024 + k] = (k < 512) ? f2[(size_t)j * 512 + k]
                                              : b2o[(size_t)j * 512 + k - 512];
    if (j == 0) {
        for (int i = threadIdx.x; i < 512; i += 256)
            hdec_p[i] = packfe(f2[59 * 512 + i], 0);
    }
}

// ---------------------------------------------------------------------------
// precompute M = comb_W[:, 8:1032] @ ctx^T  -> Mg[512][60]  (unchanged)
// ---------------------------------------------------------------------------
__global__ void __launch_bounds__(256) precomp_M(
    const float* __restrict__ comb_W,   // [512][1032]
    const float* __restrict__ ctx,      // [60][1024]
    float* __restrict__ Mg)             // [512][60]
{
    __shared__ float cw[8 * 1024];      // 32 KB: comb_W rows d0..d0+8, cols 8..1032
    const int tid = threadIdx.x, d0 = blockIdx.x * 8;
    for (int i = tid; i < 2048; i += 256) {
        int r = i >> 8, c4 = i & 255;
        float4 v = *(const float4*)&comb_W[(size_t)(d0 + r) * 1032 + 8 + 4 * c4];
        *(float4*)&cw[r * 1024 + 4 * c4] = v;
    }
    __syncthreads();
    for (int o = tid; o < 480; o += 256) {
        int dl = o / 60, j = o % 60;
        const float4* cp = (const float4*)&cw[dl * 1024];
        const float4* xp = (const float4*)(ctx + (size_t)j * 1024);
        float a = 0.f;
#pragma unroll 4
        for (int k = 0; k < 256; ++k) {
            float4 w = cp[k], x = xp[k];
            a += w.x * x.x + w.y * x.y + w.z * x.z + w.w * x.w;
        }
        Mg[(size_t)(d0 + dl) * 60 + j] = a;
    }
}

// ---------------------------------------------------------------------------
// Decoder R10: 64 blocks x 512 threads. Weights fit registers (~36 float4 per
// thread, no spill). Shuffle-tree row reductions; inp->z->softmax fused into
// one wave-0 phase (within-wave LDS ordering). 6 barriers/step; only
// cross-block payload per step is the h all-to-all (1 word/thread poll).
// ---------------------------------------------------------------------------
__global__ void __launch_bounds__(512, 1) dec_k(
    const float* __restrict__ attn_W, const float* __restrict__ attn_b,
    const float* __restrict__ comb_W, const float* __restrict__ comb_b,
    const float* __restrict__ gWih, const float* __restrict__ gWhh,
    const float* __restrict__ gbih, const float* __restrict__ gbhh,
    const float* __restrict__ outW, const float* __restrict__ outb,
    const float* __restrict__ Mg,   // [512][60]
    ull* __restrict__ hdec_p,       // [2][512]
    float* __restrict__ dout)
{
    const int tid = threadIdx.x, bid = blockIdx.x;   // 64 blocks x 512 thr
    const int lane = tid & 63, wv = tid >> 6;
    const int dbase = bid * 8;

    __shared__ float M2[512][70];                    // [M(60) | Minp(8) | pad2]
    __shared__ __align__(16) float hL[520];          // h(512) + pad
    __shared__ __align__(16) float xl[512];          // o
    __shared__ __align__(16) float awx[68];          // [aw(60); inp(8)]
    __shared__ float zd[8], zh[64];
    __shared__ float ghl[24], gil[24];
    __shared__ float biasg[24], biasi[24];
    __shared__ float cbL[512];
    __shared__ float attnbL[64], outbL[8];

    // row/seg partitions
    const int rg = tid >> 4, sg = tid & 15;   // gh/gi: 24(32) rows x 16 segs(32 elems)
    const int rz = tid >> 3, szz = tid & 7;   // z_h: 60(64) rows x 8 segs(64 elems)

    // ---- weights to registers (36 float4 / thread) ----
    float4 wo2[2];                  // logits: row wv, seg lane (8 elems)
    float4 wg8[8], wi8[8];          // gh / gi
    float4 wzh[16];                 // z h-part
    float4 wip[2];                  // z inp-part (row tid<60)
    {
        const float* wp = outW + (size_t)wv * 512 + lane * 8;
        wo2[0] = *(const float4*)wp;
        wo2[1] = *(const float4*)(wp + 4);
    }
    {
        int rr = (rg < 24) ? rg : 23;
        size_t grow = (size_t)((rr >> 3) * 512 + dbase + (rr & 7)) * 512 + sg * 32;
#pragma unroll
        for (int i = 0; i < 8; ++i) {
            wg8[i] = *(const float4*)&gWhh[grow + 4 * i];
            wi8[i] = *(const float4*)&gWih[grow + 4 * i];
        }
    }
    {
        int rr = (rz < 60) ? rz : 59;
        size_t base = (size_t)rr * 520 + 8 + szz * 64;
#pragma unroll
        for (int i = 0; i < 16; ++i)
            wzh[i] = *(const float4*)&attn_W[base + 4 * i];
    }
    {
        int rr = (tid < 60) ? tid : 59;
        wip[0] = *(const float4*)&attn_W[(size_t)rr * 520 + 0];
        wip[1] = *(const float4*)&attn_W[(size_t)rr * 520 + 4];
    }
    if (tid < 24) {
        int g2 = (tid >> 3) * 512 + dbase + (tid & 7);
        biasg[tid] = gbhh[g2];
        biasi[tid] = gbih[g2];
    }
    if (tid < 512) cbL[tid] = comb_b[tid];
    if (tid < 64) attnbL[tid] = (tid < 60) ? attn_b[tid] : 0.f;
    if (tid < 8) outbL[tid] = outb[tid];
    // M2: cols 0..59 from Mg, cols 60..67 = comb_W[:,0..8)
    for (int i = tid; i < 512 * 15; i += 512) {
        int r = i / 15, c4 = i % 15;
        float4 v = *(const float4*)&Mg[(size_t)r * 60 + 4 * c4];
        M2[r][4 * c4 + 0] = v.x; M2[r][4 * c4 + 1] = v.y;
        M2[r][4 * c4 + 2] = v.z; M2[r][4 * c4 + 3] = v.w;
    }
    for (int i = tid; i < 512 * 2; i += 512) {
        int r = i >> 1, h4 = i & 1;
        float4 v = *(const float4*)&comb_W[(size_t)r * 1032 + 4 * h4];
        M2[r][60 + 4 * h4 + 0] = v.x; M2[r][60 + 4 * h4 + 1] = v.y;
        M2[r][60 + 4 * h4 + 2] = v.z; M2[r][60 + 4 * h4 + 3] = v.w;
    }
    __syncthreads();

    for (int s = 0; s < 30; ++s) {
        // ---- cross-block hop: h (slot s&1, epoch s), 1 word/thread ----
        {
            const ull* hs = hdec_p + (size_t)(s & 1) * 512;
            ull v0 = gldll(hs + tid);
            while ((int)(v0 >> 32) != s) {
                __builtin_amdgcn_s_sleep(1);
                v0 = gldll(hs + tid);
            }
            hL[tid] = lowf(v0);
        }
        __syncthreads();

        // ---- phase A: three h-matvec partials + shuffle reductions ----
        {   // logits: one wave per row, 8 elems/lane, 6-level reduce
            float a = 0.f;
            const float4* h4p = (const float4*)&hL[lane * 8];
            float4 h0 = h4p[0], h1 = h4p[1];
            a += wo2[0].x*h0.x + wo2[0].y*h0.y + wo2[0].z*h0.z + wo2[0].w*h0.w;
            a += wo2[1].x*h1.x + wo2[1].y*h1.y + wo2[1].z*h1.z + wo2[1].w*h1.w;
#pragma unroll
            for (int off = 32; off; off >>= 1) a += __shfl_xor(a, off);
            if (lane == 0) zd[wv] = a;
        }
        {   // gh: 16-lane groups
            float a = 0.f;
            const float* hb = &hL[sg * 32];
#pragma unroll
            for (int i = 0; i < 8; ++i) {
                float4 w = wg8[i];
                float4 h4 = *(const float4*)&hb[4 * i];
                a += w.x*h4.x + w.y*h4.y + w.z*h4.z + w.w*h4.w;
            }
            a += __shfl_xor(a, 1); a += __shfl_xor(a, 2);
            a += __shfl_xor(a, 4); a += __shfl_xor(a, 8);
            if (sg == 0 && rg < 24) ghl[rg] = a;
        }
        {   // z_h: 8-lane groups
            float a = 0.f;
            const float* hb = &hL[szz * 64];
#pragma unroll
            for (int i = 0; i < 16; ++i) {
                float4 w = wzh[i];
                float4 h4 = *(const float4*)&hb[4 * i];
                a += w.x*h4.x + w.y*h4.y + w.z*h4.z + w.w*h4.w;
            }
            a += __shfl_xor(a, 1); a += __shfl_xor(a, 2); a += __shfl_xor(a, 4);
            if (szz == 0 && rz < 60) zh[rz] = a;
        }
        __syncthreads();

        // ---- phase BC (wave 0): inp -> z finalize -> softmax60 ----
        if (wv == 0) {
            if (lane < 8) {
                float v;
                if (s > 0) {
                    float a = zd[lane] + outbL[lane];
                    float m = a;
                    m = fmaxf(m, __shfl_xor(m, 1));
                    m = fmaxf(m, __shfl_xor(m, 2));
                    m = fmaxf(m, __shfl_xor(m, 4));
                    float e = __expf(a - m);
                    float ss2 = e;
                    ss2 += __shfl_xor(ss2, 1);
                    ss2 += __shfl_xor(ss2, 2);
                    ss2 += __shfl_xor(ss2, 4);
                    v = a - m - __logf(ss2);
                    if (bid == 0) dout[(s - 1) * 8 + lane] = v;
                } else {
                    v = (lane == 7) ? 1.f : 0.f;
                }
                awx[60 + lane] = v;
            }
            // z = zh + b + attn_W[:,0:8] @ inp  (same-wave LDS ordering: the
            // awx writes above issue before these reads in lockstep order)
            float z = -1e30f;
            if (lane < 60) {
                z = zh[lane] + attnbL[lane]
                  + wip[0].x * awx[60] + wip[0].y * awx[61]
                  + wip[0].z * awx[62] + wip[0].w * awx[63]
                  + wip[1].x * awx[64] + wip[1].y * awx[65]
                  + wip[1].z * awx[66] + wip[1].w * awx[67];
            }
            float m = z;
#pragma unroll
            for (int off = 32; off; off >>= 1) m = fmaxf(m, __shfl_xor(m, off));
            float e = (lane < 60) ? __expf(z - m) : 0.f;
            float ss2 = e;
#pragma unroll
            for (int off = 32; off; off >>= 1) ss2 += __shfl_xor(ss2, off);
            if (lane < 60) awx[lane] = e / ss2;
        }
        __syncthreads();

        // ---- phase E: o = relu(M2 @ [aw; inp] + comb_b), 1 dim/thread ----
        {
            float a = cbL[tid];
            const float2* mrow = (const float2*)&M2[tid][0];
            const float2* xv = (const float2*)&awx[0];
#pragma unroll
            for (int jj = 0; jj < 34; ++jj) {
                float2 mm = mrow[jj], xx = xv[jj];
                a += mm.x * xx.x + mm.y * xx.y;
            }
            xl[tid] = fmaxf(a, 0.f);
        }
        __syncthreads();

        // ---- phase F: gi = gWih @ o, 16-lane groups ----
        {
            float a = 0.f;
            const float* ob = &xl[sg * 32];
#pragma unroll
            for (int i = 0; i < 8; ++i) {
                float4 w = wi8[i];
                float4 o4 = *(const float4*)&ob[4 * i];
                a += w.x*o4.x + w.y*o4.y + w.z*o4.z + w.w*o4.w;
            }
            a += __shfl_xor(a, 1); a += __shfl_xor(a, 2);
            a += __shfl_xor(a, 4); a += __shfl_xor(a, 8);
            if (sg == 0 && rg < 24) gil[rg] = a;
        }
        __syncthreads();

        // ---- phase G: GRU combine + publish (8 threads) ----
        if (tid < 8) {
            float gh0 = biasg[tid] + ghl[tid];
            float gh1 = biasg[8 + tid] + ghl[8 + tid];
            float gh2 = biasg[16 + tid] + ghl[16 + tid];
            float gi0 = biasi[tid] + gil[tid];
            float gi1 = biasi[8 + tid] + gil[8 + tid];
            float gi2 = biasi[16 + tid] + gil[16 + tid];
            float r_ = sigf(gi0 + gh0);
            float z_ = sigf(gi1 + gh1);
            float n_ = tanh_f(gi2 + r_ * gh2);
            float hnew = (1.f - z_) * n_ + z_ * hL[dbase + tid];
            gstll(&hdec_p[(size_t)((s + 1) & 1) * 512 + dbase + tid], packfe(hnew, s + 1));
        }
        __syncthreads();   // protect hL/awx/xl before next-step overwrite
    }

    // epilogue: logits for s=29 (block 0 only)
    if (bid == 0) {
        {
            const ull* hs = hdec_p + (size_t)(30 & 1) * 512;
            ull v0 = gldll(hs + tid);
            while ((int)(v0 >> 32) != 30) {
                __builtin_amdgcn_s_sleep(1);
                v0 = gldll(hs + tid);
            }
            hL[tid] = lowf(v0);
        }
        __syncthreads();
        {
            float a = 0.f;
            const float4* h4p = (const float4*)&hL[lane * 8];
            float4 h0 = h4p[0], h1 = h4p[1];
            a += wo2[0].x*h0.x + wo2[0].y*h0.y + wo2[0].z*h0.z + wo2[0].w*h0.w;
            a += wo2[1].x*h1.x + wo2[1].y*h1.y + wo2[1].z*h1.z + wo2[1].w*h1.w;
#pragma unroll
            for (int off = 32; off; off >>= 1) a += __shfl_xor(a, off);
            if (lane == 0) zd[wv] = a;
        }
        __syncthreads();
        if (tid < 8) {
            float a = zd[tid] + outbL[tid];
            float m = a;
            m = fmaxf(m, __shfl_xor(m, 1));
            m = fmaxf(m, __shfl_xor(m, 2));
            m = fmaxf(m, __shfl_xor(m, 4));
            float e = __expf(a - m);
            float ss2 = e;
            ss2 += __shfl_xor(ss2, 1);
            ss2 += __shfl_xor(ss2, 2);
            ss2 += __shfl_xor(ss2, 4);
            dout[29 * 8 + tid] = a - m - __logf(ss2);
        }
    }
}

// ---------------------------------------------------------------------------
extern "C" void kernel_launch(void* const* d_in, const int* in_sizes, int n_in,
                              void* d_out, int out_size, void* d_ws, size_t ws_size,
                              hipStream_t stream) {
    (void)in_sizes; (void)n_in; (void)out_size; (void)ws_size;
    const float* data    = (const float*)d_in[0];
    const float* enc_Wih = (const float*)d_in[1];
    const float* enc_Whh = (const float*)d_in[2];
    const float* enc_bih = (const float*)d_in[3];
    const float* enc_bhh = (const float*)d_in[4];
    const float* p1f_Wih = (const float*)d_in[5];
    const float* p1f_Whh = (const float*)d_in[6];
    const float* p1f_bih = (const float*)d_in[7];
    const float* p1f_bhh = (const float*)d_in[8];
    const float* p1b_Wih = (const float*)d_in[9];
    const float* p1b_Whh = (const float*)d_in[10];
    const float* p1b_bih = (const float*)d_in[11];
    const float* p1b_bhh = (const float*)d_in[12];
    const float* p2f_Wih = (const float*)d_in[13];
    const float* p2f_Whh = (const float*)d_in[14];
    const float* p2f_bih = (const float*)d_in[15];
    const float* p2f_bhh = (const float*)d_in[16];
    const float* p2b_Wih = (const float*)d_in[17];
    const float* p2b_Whh = (const float*)d_in[18];
    const float* p2b_bih = (const float*)d_in[19];
    const float* p2b_bhh = (const float*)d_in[20];
    const float* attn_W  = (const float*)d_in[21];
    const float* attn_b  = (const float*)d_in[22];
    const float* comb_W  = (const float*)d_in[23];
    const float* comb_b  = (const float*)d_in[24];
    const float* gru_Wih = (const float*)d_in[25];
    const float* gru_Whh = (const float*)d_in[26];
    const float* gru_bih = (const float*)d_in[27];
    const float* gru_bhh = (const float*)d_in[28];
    const float* out_W   = (const float*)d_in[29];
    const float* out_b   = (const float*)d_in[30];

    float* ws = (float*)d_ws;
    // zeroed region [0 .. 256000)
    ull* hbufF   = (ull*)ws;                 // 245760 floats = [2][15][4096] ull
    ull* hp1     = (ull*)(ws + 245760);      // 4096 floats = [2][2][512] ull
    ull* hp2     = (ull*)(ws + 249856);      // 4096 floats
    ull* hdec_p  = (ull*)(ws + 253952);      // 2048 floats = [2][512] ull -> end 256000
    // non-zeroed scratch
    float* henc  = ws + 256000;              // 122880
    float* xp1f  = ws + 378880;              // 245760
    float* xp1b  = ws + 624640;              // 245760
    float* f1    = ws + 870400;              // 61440
    float* b1o   = ws + 931840;              // 61440
    float* x2    = ws + 993280;              // 122880
    float* xp2f  = ws + 1116160;             // 122880
    float* xp2b  = ws + 1239040;             // 122880
    float* f2    = ws + 1361920;             // 30720
    float* b2o   = ws + 1392640;             // 30720
    float* ctxb  = ws + 1423360;             // 61440
    float* Mg    = ws + 1484800;             // 30720 -> end 1515520

    init_k<<<256, 256, 0, stream>>>(ws);

    enc_all<<<240, 256, 0, stream>>>(data, enc_Wih, enc_Whh, enc_bih, enc_bhh,
                                     hbufF, henc);
    gemm_xp2<<<256, 256, 0, stream>>>(henc, 120, 1024, 128,
                                      p1f_Wih, p1f_bih, p1f_bhh, xp1f,
                                      p1b_Wih, p1b_bih, p1b_bhh, xp1b);
    pyr_rec<<<128, 256, 0, stream>>>(xp1f, xp1b, p1f_Whh, p1b_Whh, hp1, f1, b1o, 120);
    x2_assemble<<<60, 256, 0, stream>>>(f1, b1o, x2);
    gemm_xp2<<<128, 256, 0, stream>>>(x2, 60, 2048, 64,
                                      p2f_Wih, p2f_bih, p2f_bhh, xp2f,
                                      p2b_Wih, p2b_bih, p2b_bhh, xp2b);
    pyr_rec<<<128, 256, 0, stream>>>(xp2f, xp2b, p2f_Whh, p2b_Whh, hp2, f2, b2o, 60);
    ctx_k<<<60, 256, 0, stream>>>(f2, b2o, ctxb, hdec_p);
    precomp_M<<<64, 256, 0, stream>>>(comb_W, ctxb, Mg);
    dec_k<<<64, 512, 0, stream>>>(attn_W, attn_b, comb_W, comb_b,
                                  gru_Wih, gru_Whh, gru_bih, gru_bhh,
                                  out_W, out_b, Mg, hdec_p,
                                  (float*)d_out);
}

// Round 6
// 1192.418 us; speedup vs baseline: 1.5601x; 1.0829x over previous
//
#include <hip/hip_runtime.h>
#include <math.h>

// Model dims: H=512 D=128 L=8 T=64 W=240 CTX=60 NSTEPS=30

typedef __attribute__((ext_vector_type(8))) short short8;
typedef __attribute__((ext_vector_type(4))) float floatx4;
typedef unsigned long long ull;

__device__ __forceinline__ float sigf(float x) { return 1.f / (1.f + __expf(-x)); }
__device__ __forceinline__ float tanh_f(float x) {
    float e = __expf(2.f * x);
    return 1.f - 2.f / (e + 1.f);
}
__device__ __forceinline__ unsigned short f2b(float x) {   // fp32 -> bf16 RNE
    unsigned u = __float_as_uint(x);
    unsigned r = (u + 0x7FFFu + ((u >> 16) & 1u)) >> 16;
    return (unsigned short)r;
}

// RELAXED agent-scope atomics only (acquire/release emit buffer_inv/wbl2 on
// gfx950 and trash the XCD L2). Cross-block payloads are {epoch|data} ull
// words polled directly (data+readiness in one MALL round trip), batch-polled.
// R11: dec_k's R10 rewrite regressed LDS bank conflicts 125x (block-contiguous
// segment reads hL[sg*32+..]/hL[szz*64+..] alias all segments to the same
// banks -> 8-16-way conflicts; SQ_LDS_BANK_CONFLICT 1.4e7 ~ 91us/dispatch).
// This round restores mod-32 interleaved k-mappings (k = 4*seg + stride*i) on
// every matvec and transposes the apply matrix (M2T[k][tid]: lane-consecutive
// scalar reads, conflict-free) so ALL per-step LDS reads are <=2-way.
__device__ __forceinline__ float gld(const float* p) {
    return __hip_atomic_load(p, __ATOMIC_RELAXED, __HIP_MEMORY_SCOPE_AGENT);
}
__device__ __forceinline__ void gst(float* p, float v) {
    __hip_atomic_store(p, v, __ATOMIC_RELAXED, __HIP_MEMORY_SCOPE_AGENT);
}
__device__ __forceinline__ ull gldll(const ull* p) {
    return __hip_atomic_load(p, __ATOMIC_RELAXED, __HIP_MEMORY_SCOPE_AGENT);
}
__device__ __forceinline__ void gstll(ull* p, ull v) {
    __hip_atomic_store(p, v, __ATOMIC_RELAXED, __HIP_MEMORY_SCOPE_AGENT);
}
__device__ __forceinline__ ull packfe(float d, int ep) {
    return ((ull)(unsigned)ep << 32) | (ull)__float_as_uint(d);
}
__device__ __forceinline__ float lowf(ull v) { return __uint_as_float((unsigned)v); }

// ---------------------------------------------------------------------------
// init: zero [hbufF(245760f) | hp1(4096) | hp2(4096) | hdec(2048)] = 256000 f
// ---------------------------------------------------------------------------
__global__ void init_k(float* __restrict__ ws) {
    for (int i = blockIdx.x * blockDim.x + threadIdx.x; i < 256000; i += gridDim.x * blockDim.x)
        ws[i] = 0.f;
}

// ---------------------------------------------------------------------------
// Encoder, ONE persistent launch, 64 steps, bf16 MFMA (unchanged from R9).
// ---------------------------------------------------------------------------
__global__ void __launch_bounds__(256, 1) enc_all(
    const float* __restrict__ data,
    const float* __restrict__ Wih, const float* __restrict__ Whh,
    const float* __restrict__ bih, const float* __restrict__ bhh,
    ull* __restrict__ hbufF,        // [2][15][4096] {epoch|bf16x2}
    float* __restrict__ henc)       // [240][512] fp32 final h
{
    __shared__ short act2[20 * 64 * 8];
    __shared__ float gw[4][640];
    __shared__ float cs[512];
    __shared__ short hw[4][16][8];
    __shared__ float biasL[4][4][8];

    const int tid = threadIdx.x;
    const int fg = blockIdx.x >> 4, ds = blockIdx.x & 15;
    const int w = tid >> 6, lane = tid & 63;
    const int n = lane & 15, q = lane >> 4;

    short8 bfrag[2][20];
#pragma unroll
    for (int nt = 0; nt < 2; ++nt) {
        int rr = nt * 16 + n;
        int g = rr >> 3, dp = rr & 7;
        int grow = g * 512 + ds * 32 + w * 8 + dp;
#pragma unroll
        for (int kt = 0; kt < 20; ++kt) {
            int k0 = kt * 32 + q * 8;
            const float* src = (k0 < 512) ? (Whh + (size_t)grow * 512 + k0)
                                          : (Wih + (size_t)grow * 128 + (k0 - 512));
            float4 lo = *(const float4*)src;
            float4 hi = *(const float4*)(src + 4);
            short8 bf;
            bf[0] = (short)f2b(lo.x); bf[1] = (short)f2b(lo.y);
            bf[2] = (short)f2b(lo.z); bf[3] = (short)f2b(lo.w);
            bf[4] = (short)f2b(hi.x); bf[5] = (short)f2b(hi.y);
            bf[6] = (short)f2b(hi.z); bf[7] = (short)f2b(hi.w);
            bfrag[nt][kt] = bf;
        }
    }
    if (tid < 128) {
        int w2 = tid >> 5, rr = tid & 31;
        int g = rr >> 3, dp = rr & 7;
        int grow = g * 512 + ds * 32 + w2 * 8 + dp;
        biasL[w2][g][dp] = bih[grow] + bhh[grow];
    }
    for (int i = tid; i < 512; i += 256) cs[i] = 0.f;
    __syncthreads();

    unsigned* a2u = (unsigned*)act2;

    for (int t = 0; t < 64; ++t) {
        // x prefetch FIRST: global loads issue, latency hides under the h poll
        const int kt2 = tid >> 6, l2 = tid & 63, f2v = l2 & 15, q2 = l2 >> 4;
        const float* xs = data + ((size_t)t * 240 + fg * 16 + f2v) * 128 + kt2 * 32 + q2 * 8;
        float4 lo = *(const float4*)xs;
        float4 hi = *(const float4*)(xs + 4);

        // h gather: batch-poll 16 {epoch|bf16x2} words (ONE MALL window)
        {
            const ull* hsrc = hbufF + (size_t)((t & 1) * 15 + fg) * 4096;
            ull v[16];
            for (;;) {
                bool ok = true;
#pragma unroll
                for (int k2 = 0; k2 < 16; ++k2) {
                    v[k2] = gldll(hsrc + tid + 256 * k2);
                    ok &= ((int)(v[k2] >> 32) == t);
                }
                if (ok) break;
                __builtin_amdgcn_s_sleep(1);
            }
#pragma unroll
            for (int k2 = 0; k2 < 16; ++k2)
                a2u[tid + 256 * k2] = (unsigned)v[k2];
        }
        {
            short8 xp;
            xp[0] = (short)f2b(lo.x); xp[1] = (short)f2b(lo.y);
            xp[2] = (short)f2b(lo.z); xp[3] = (short)f2b(lo.w);
            xp[4] = (short)f2b(hi.x); xp[5] = (short)f2b(hi.y);
            xp[6] = (short)f2b(hi.z); xp[7] = (short)f2b(hi.w);
            *(short8*)&act2[((16 + kt2) * 64 + l2) * 8] = xp;
        }
        __syncthreads();

        floatx4 acc0 = {0.f, 0.f, 0.f, 0.f};
        floatx4 acc1 = {0.f, 0.f, 0.f, 0.f};
#pragma unroll
        for (int kt = 0; kt < 20; ++kt) {
            short8 a = *(short8*)&act2[(kt * 64 + lane) * 8];
            acc0 = __builtin_amdgcn_mfma_f32_16x16x32_bf16(a, bfrag[0][kt], acc0, 0, 0, 0);
            acc1 = __builtin_amdgcn_mfma_f32_16x16x32_bf16(a, bfrag[1][kt], acc1, 0, 0, 0);
        }
        *(floatx4*)&gw[w][(0 * 16 + n) * 20 + 4 * q] = acc0;
        *(floatx4*)&gw[w][(1 * 16 + n) * 20 + 4 * q] = acc1;

        int nb = (t + 1) & 1;
#pragma unroll
        for (int it = 0; it < 2; ++it) {
            int f = lane & 15, dp = q + 4 * it;
            float gi = gw[w][(0 * 8 + dp) * 20 + f] + biasL[w][0][dp];
            float gf = gw[w][(1 * 8 + dp) * 20 + f] + biasL[w][1][dp];
            float gg = gw[w][(2 * 8 + dp) * 20 + f] + biasL[w][2][dp];
            float go = gw[w][(3 * 8 + dp) * 20 + f] + biasL[w][3][dp];
            int ci = f * 32 + w * 8 + dp;
            float cc = cs[ci];
            float cn = sigf(gf) * cc + sigf(gi) * tanh_f(gg);
            float hn = sigf(go) * tanh_f(cn);
            cs[ci] = cn;
            hw[w][f][dp] = (short)f2b(hn);
            if (t == 63)
                gst(&henc[(size_t)(fg * 16 + f) * 512 + ds * 32 + w * 8 + dp], hn);
        }
        if (lane < 16) {
            const unsigned* hwu = (const unsigned*)&hw[w][lane][0];
            ull* dst = hbufF + (size_t)(nb * 15 + fg) * 4096 + (ds * 64 + w * 16 + lane) * 4;
            const ull ep = ((ull)(unsigned)(t + 1)) << 32;
#pragma unroll
            for (int r = 0; r < 4; ++r)
                gstll(dst + r, ep | (ull)hwu[r]);
        }
        __syncthreads();
    }
}

// ---------------------------------------------------------------------------
// xp GEMM, F/B pair fused into one launch (unchanged).
// ---------------------------------------------------------------------------
__global__ void __launch_bounds__(256) gemm_xp2(
    const float* __restrict__ A, int M, int K, int halfgrid,
    const float* __restrict__ WvF, const float* __restrict__ baF,
    const float* __restrict__ bbF, float* __restrict__ CF,
    const float* __restrict__ WvB, const float* __restrict__ baB,
    const float* __restrict__ bbB, float* __restrict__ CB)
{
    __shared__ float At[16][66];
    __shared__ float Wt[128][66];
    const int tid = threadIdx.x;
    int bgl = blockIdx.x;
    const int rev = (bgl >= halfgrid) ? 1 : 0;
    if (rev) bgl -= halfgrid;
    const float* Wv = rev ? WvB : WvF;
    const float* ba = rev ? baB : baF;
    const float* bb = rev ? bbB : bbF;
    float* C        = rev ? CB : CF;

    const int nt = bgl & 15, mt = bgl >> 4;
    const int rp = tid >> 2, fq = tid & 3;
    const int lr0 = 2 * rp, lr1 = lr0 + 1;
    const int n0 = nt * 128 + lr0, n1 = n0 + 1;

    float acc0[4], acc1[4];
    {
        float b0 = ba[n0] + bb[n0], b1 = ba[n1] + bb[n1];
#pragma unroll
        for (int j = 0; j < 4; ++j) { acc0[j] = b0; acc1[j] = b1; }
    }

    for (int kt = 0; kt < K; kt += 64) {
        {
            int f = tid >> 4, c4 = tid & 15;
            int m = mt * 16 + f;
            float4 v = make_float4(0.f, 0.f, 0.f, 0.f);
            if (m < M) {
                int ar = rev ? (M - 1 - m) : m;
                v = ((const float4*)(A + (size_t)ar * K + kt))[c4];
            }
            At[f][c4 * 4 + 0] = v.x; At[f][c4 * 4 + 1] = v.y;
            At[f][c4 * 4 + 2] = v.z; At[f][c4 * 4 + 3] = v.w;
        }
        for (int i = tid; i < 2048; i += 256) {
            int lr = i >> 4, c4 = i & 15;
            float4 v = ((const float4*)(Wv + (size_t)(nt * 128 + lr) * K + kt))[c4];
            Wt[lr][c4 * 4 + 0] = v.x; Wt[lr][c4 * 4 + 1] = v.y;
            Wt[lr][c4 * 4 + 2] = v.z; Wt[lr][c4 * 4 + 3] = v.w;
        }
        __syncthreads();
        const float2* w0p = (const float2*)(&Wt[lr0][0]);
        const float2* w1p = (const float2*)(&Wt[lr1][0]);
#pragma unroll 8
        for (int kh = 0; kh < 32; ++kh) {
            float2 w0 = w0p[kh], w1 = w1p[kh];
#pragma unroll
            for (int j = 0; j < 4; ++j) {
                float2 av = ((const float2*)(&At[4 * fq + j][0]))[kh];
                acc0[j] += w0.x * av.x + w0.y * av.y;
                acc1[j] += w1.x * av.x + w1.y * av.y;
            }
        }
        __syncthreads();
    }
#pragma unroll
    for (int j = 0; j < 4; ++j) {
        int m = mt * 16 + 4 * fq + j;
        if (m < M) {
            C[(size_t)m * 2048 + n0] = acc0[j];
            C[(size_t)m * 2048 + n1] = acc1[j];
        }
    }
}

// ---------------------------------------------------------------------------
// Pyramidal bi-LSTM (unchanged).
// ---------------------------------------------------------------------------
__global__ void __launch_bounds__(256, 1) pyr_rec(
    const float* __restrict__ xpF, const float* __restrict__ xpB,
    const float* __restrict__ WhhF, const float* __restrict__ WhhB,
    ull* __restrict__ hp,      // [dir][2][512]
    float* __restrict__ outF, float* __restrict__ outB,
    int steps)
{
    const int tid = threadIdx.x;
    const int dir = blockIdx.x >> 6, blk = blockIdx.x & 63;
    const float* xp  = dir ? xpB : xpF;
    const float* Whh = dir ? WhhB : WhhF;
    float* outp = dir ? outB : outF;
    ull* hpd = hp + (size_t)dir * 1024;

    __shared__ __align__(16) float hcur[512];
    __shared__ float red[32][9];
    __shared__ float gv[32];

    const int lr = tid & 31, seg = tid >> 5;
    const int grow = (lr >> 3) * 512 + blk * 8 + (lr & 7);
    float4 wl4[16];
#pragma unroll
    for (int j = 0; j < 16; ++j)
        wl4[j] = *(const float4*)&Whh[(size_t)grow * 512 + 4 * seg + 32 * j];

    const int growx = (tid >> 3) * 512 + blk * 8 + (tid & 7);   // for tid<32
    float creg = 0.f;
    __syncthreads();

    for (int t = 0; t < steps; ++t) {
        float xg = 0.f;
        if (tid < 32) xg = xp[(size_t)t * 2048 + growx];   // prefetch (no h dep)
        {
            const ull* base = hpd + (size_t)(t & 1) * 512;
            ull v0 = gldll(base + tid), v1 = gldll(base + tid + 256);
            while (((int)(v0 >> 32) != t) | ((int)(v1 >> 32) != t)) {
                __builtin_amdgcn_s_sleep(1);
                v0 = gldll(base + tid);
                v1 = gldll(base + tid + 256);
            }
            hcur[tid]       = lowf(v0);
            hcur[tid + 256] = lowf(v1);
        }
        __syncthreads();

        float a = 0.f;
#pragma unroll
        for (int j = 0; j < 16; ++j) {
            float4 w = wl4[j];
            float4 h4 = *(const float4*)&hcur[4 * seg + 32 * j];
            a += w.x*h4.x + w.y*h4.y + w.z*h4.z + w.w*h4.w;
        }
        red[lr][seg] = a;
        __syncthreads();

        if (tid < 32) {
            float g = xg;
#pragma unroll
            for (int s2 = 0; s2 < 8; ++s2) g += red[tid][s2];
            gv[tid] = g;
        }
        __syncthreads();
        if (tid < 8) {
            float i_ = sigf(gv[tid]), f_ = sigf(gv[8 + tid]);
            float g_ = tanh_f(gv[16 + tid]), o_ = sigf(gv[24 + tid]);
            creg = f_ * creg + i_ * g_;
            float hn = o_ * tanh_f(creg);
            int d = blk * 8 + tid;
            gstll(&hpd[((t + 1) & 1) * 512 + d], packfe(hn, t + 1));
            int row = dir ? (steps - 1 - t) : t;
            outp[(size_t)row * 512 + d] = hn;
        }
        __syncthreads();
    }
}

__global__ void x2_assemble(const float* __restrict__ f1, const float* __restrict__ b1o,
                            float* __restrict__ x2)
{
    int j = blockIdx.x;
    for (int k = threadIdx.x; k < 2048; k += 256) {
        int q = k >> 9, r = k & 511;
        const float* src = (q & 1) ? b1o : f1;
        int row = 2 * j + (q >> 1);
        x2[(size_t)j * 2048 + k] = src[(size_t)row * 512 + r];
    }
}

// ctx assemble + publish hdec slot 0 with epoch 0
__global__ void ctx_k(const float* __restrict__ f2, const float* __restrict__ b2o,
                      float* __restrict__ ctx, ull* __restrict__ hdec_p)
{
    int j = blockIdx.x;
    for (int k = threadIdx.x; k < 1024; k += 256)
        ctx[(size_t)j * 1024 + k] = (k < 512) ? f2[(size_t)j * 512 + k]
                                              : b2o[(size_t)j * 512 + k - 512];
    if (j == 0) {
        for (int i = threadIdx.x; i < 512; i += 256)
            hdec_p[i] = packfe(f2[59 * 512 + i], 0);
    }
}

// ---------------------------------------------------------------------------
// precompute M^T: MgT[60][512], MgT[j][d] = sum_k comb_W[d][8+k] * ctx[j][k]
// (transposed output so dec_k's apply reads are lane-consecutive).
// ---------------------------------------------------------------------------
__global__ void __launch_bounds__(256) precomp_M(
    const float* __restrict__ comb_W,   // [512][1032]
    const float* __restrict__ ctx,      // [60][1024]
    float* __restrict__ MgT)            // [60][512]
{
    __shared__ float cw[8 * 1024];      // 32 KB: comb_W rows d0..d0+8, cols 8..1032
    const int tid = threadIdx.x, d0 = blockIdx.x * 8;
    for (int i = tid; i < 2048; i += 256) {
        int r = i >> 8, c4 = i & 255;
        float4 v = *(const float4*)&comb_W[(size_t)(d0 + r) * 1032 + 8 + 4 * c4];
        *(float4*)&cw[r * 1024 + 4 * c4] = v;
    }
    __syncthreads();
    for (int o = tid; o < 480; o += 256) {
        int dl = o / 60, j = o % 60;
        const float4* cp = (const float4*)&cw[dl * 1024];
        const float4* xp = (const float4*)(ctx + (size_t)j * 1024);
        float a = 0.f;
#pragma unroll 4
        for (int k = 0; k < 256; ++k) {
            float4 w = cp[k], x = xp[k];
            a += w.x * x.x + w.y * x.y + w.z * x.z + w.w * x.w;
        }
        MgT[(size_t)j * 512 + (d0 + dl)] = a;
    }
}

// ---------------------------------------------------------------------------
// Decoder R11: 64 blocks x 512 threads, register weights, shuffle reductions.
// ALL per-step LDS reads are conflict-free / <=2-way:
//  - gh/gi:  k = 4*sg + 64*i   (16 float4 starts span 256B -> 2-way, free)
//  - z_h:    k = 4*szz + 32*i  (8 float4 starts span 128B -> conflict-free)
//  - logits: k = 4*lane + 256*i (contiguous 16B-stride wave read)
//  - apply:  M2T[k][tid] scalar (lane-consecutive banks, conflict-free)
// Only cross-block payload per step is the h all-to-all (1 word/thread poll).
// ---------------------------------------------------------------------------
__global__ void __launch_bounds__(512, 1) dec_k(
    const float* __restrict__ attn_W, const float* __restrict__ attn_b,
    const float* __restrict__ comb_W, const float* __restrict__ comb_b,
    const float* __restrict__ gWih, const float* __restrict__ gWhh,
    const float* __restrict__ gbih, const float* __restrict__ gbhh,
    const float* __restrict__ outW, const float* __restrict__ outb,
    const float* __restrict__ MgT,  // [60][512]
    ull* __restrict__ hdec_p,       // [2][512]
    float* __restrict__ dout)
{
    const int tid = threadIdx.x, bid = blockIdx.x;   // 64 blocks x 512 thr
    const int lane = tid & 63, wv = tid >> 6;
    const int dbase = bid * 8;

    __shared__ float M2T[68][512];                   // rows: [M(60) | Minp(8)]
    __shared__ __align__(16) float hL[520];          // h(512) + pad
    __shared__ __align__(16) float xl[512];          // o
    __shared__ __align__(16) float awx[68];          // [aw(60); inp(8)]
    __shared__ float zd[8], zh[64];
    __shared__ float ghl[24], gil[24];
    __shared__ float biasg[24], biasi[24];
    __shared__ float cbL[512];
    __shared__ float attnbL[64], outbL[8];

    // row/seg partitions
    const int rg = tid >> 4, sg = tid & 15;   // gh/gi: 24(32) rows x 16 segs
    const int rz = tid >> 3, szz = tid & 7;   // z_h: 60(64) rows x 8 segs

    // ---- weights to registers (interleaved k-mappings) ----
    float4 wo2[2];                  // logits row wv: k = 4*lane + 256*i
    float4 wg8[8], wi8[8];          // gh/gi row rg:  k = 4*sg + 64*i
    float4 wzh[16];                 // z_h row rz:    k = 4*szz + 32*i
    float4 wip[2];                  // z inp-part (row tid<60)
    {
        const float* wp = outW + (size_t)wv * 512 + 4 * lane;
        wo2[0] = *(const float4*)wp;
        wo2[1] = *(const float4*)(wp + 256);
    }
    {
        int rr = (rg < 24) ? rg : 23;
        size_t grow = (size_t)((rr >> 3) * 512 + dbase + (rr & 7)) * 512 + 4 * sg;
#pragma unroll
        for (int i = 0; i < 8; ++i) {
            wg8[i] = *(const float4*)&gWhh[grow + 64 * i];
            wi8[i] = *(const float4*)&gWih[grow + 64 * i];
        }
    }
    {
        int rr = (rz < 60) ? rz : 59;
        size_t base = (size_t)rr * 520 + 8 + 4 * szz;
#pragma unroll
        for (int i = 0; i < 16; ++i)
            wzh[i] = *(const float4*)&attn_W[base + 32 * i];
    }
    {
        int rr = (tid < 60) ? tid : 59;
        wip[0] = *(const float4*)&attn_W[(size_t)rr * 520 + 0];
        wip[1] = *(const float4*)&attn_W[(size_t)rr * 520 + 4];
    }
    if (tid < 24) {
        int g2 = (tid >> 3) * 512 + dbase + (tid & 7);
        biasg[tid] = gbhh[g2];
        biasi[tid] = gbih[g2];
    }
    cbL[tid] = comb_b[tid];
    if (tid < 64) attnbL[tid] = (tid < 60) ? attn_b[tid] : 0.f;
    if (tid < 8) outbL[tid] = outb[tid];
    // M2T rows 0..59 from MgT (coalesced), rows 60..67 = comb_W cols 0..8
    for (int i = tid; i < 7680; i += 512) {
        int j = i >> 7, c4 = i & 127;
        *(float4*)&M2T[j][4 * c4] = *(const float4*)&MgT[(size_t)j * 512 + 4 * c4];
    }
    for (int i = tid; i < 4096; i += 512) {
        int r = i >> 3, c = i & 7;
        M2T[60 + c][r] = comb_W[(size_t)r * 1032 + c];
    }
    __syncthreads();

    for (int s = 0; s < 30; ++s) {
        // ---- cross-block hop: h (slot s&1, epoch s), 1 word/thread ----
        {
            const ull* hs = hdec_p + (size_t)(s & 1) * 512;
            ull v0 = gldll(hs + tid);
            while ((int)(v0 >> 32) != s) {
                __builtin_amdgcn_s_sleep(1);
                v0 = gldll(hs + tid);
            }
            hL[tid] = lowf(v0);
        }
        __syncthreads();

        // ---- phase A: three h-matvec partials + shuffle reductions ----
        {   // logits: one wave per row, contiguous 16B-stride reads
            float a = 0.f;
            float4 h0 = *(const float4*)&hL[4 * lane];
            float4 h1 = *(const float4*)&hL[4 * lane + 256];
            a += wo2[0].x*h0.x + wo2[0].y*h0.y + wo2[0].z*h0.z + wo2[0].w*h0.w;
            a += wo2[1].x*h1.x + wo2[1].y*h1.y + wo2[1].z*h1.z + wo2[1].w*h1.w;
#pragma unroll
            for (int off = 32; off; off >>= 1) a += __shfl_xor(a, off);
            if (lane == 0) zd[wv] = a;
        }
        {   // gh: 16 segs, k = 4*sg + 64*i
            float a = 0.f;
#pragma unroll
            for (int i = 0; i < 8; ++i) {
                float4 w = wg8[i];
                float4 h4 = *(const float4*)&hL[4 * sg + 64 * i];
                a += w.x*h4.x + w.y*h4.y + w.z*h4.z + w.w*h4.w;
            }
            a += __shfl_xor(a, 1); a += __shfl_xor(a, 2);
            a += __shfl_xor(a, 4); a += __shfl_xor(a, 8);
            if (sg == 0 && rg < 24) ghl[rg] = a;
        }
        {   // z_h: 8 segs, k = 4*szz + 32*i
            float a = 0.f;
#pragma unroll
            for (int i = 0; i < 16; ++i) {
                float4 w = wzh[i];
                float4 h4 = *(const float4*)&hL[4 * szz + 32 * i];
                a += w.x*h4.x + w.y*h4.y + w.z*h4.z + w.w*h4.w;
            }
            a += __shfl_xor(a, 1); a += __shfl_xor(a, 2); a += __shfl_xor(a, 4);
            if (szz == 0 && rz < 60) zh[rz] = a;
        }
        __syncthreads();

        // ---- phase BC (wave 0): inp -> z finalize -> softmax60 ----
        if (wv == 0) {
            if (lane < 8) {
                float v;
                if (s > 0) {
                    float a = zd[lane] + outbL[lane];
                    float m = a;
                    m = fmaxf(m, __shfl_xor(m, 1));
                    m = fmaxf(m, __shfl_xor(m, 2));
                    m = fmaxf(m, __shfl_xor(m, 4));
                    float e = __expf(a - m);
                    float ss2 = e;
                    ss2 += __shfl_xor(ss2, 1);
                    ss2 += __shfl_xor(ss2, 2);
                    ss2 += __shfl_xor(ss2, 4);
                    v = a - m - __logf(ss2);
                    if (bid == 0) dout[(s - 1) * 8 + lane] = v;
                } else {
                    v = (lane == 7) ? 1.f : 0.f;
                }
                awx[60 + lane] = v;
            }
            // z = zh + b + attn_W[:,0:8] @ inp  (same-wave LDS ordering)
            float z = -1e30f;
            if (lane < 60) {
                z = zh[lane] + attnbL[lane]
                  + wip[0].x * awx[60] + wip[0].y * awx[61]
                  + wip[0].z * awx[62] + wip[0].w * awx[63]
                  + wip[1].x * awx[64] + wip[1].y * awx[65]
                  + wip[1].z * awx[66] + wip[1].w * awx[67];
            }
            float m = z;
#pragma unroll
            for (int off = 32; off; off >>= 1) m = fmaxf(m, __shfl_xor(m, off));
            float e = (lane < 60) ? __expf(z - m) : 0.f;
            float ss2 = e;
#pragma unroll
            for (int off = 32; off; off >>= 1) ss2 += __shfl_xor(ss2, off);
            if (lane < 60) awx[lane] = e / ss2;
        }
        __syncthreads();

        // ---- phase E: o = relu(M2T^T @ [aw; inp] + comb_b), 1 dim/thread,
        //      lane-consecutive scalar reads (conflict-free) ----
        {
            float a = cbL[tid];
#pragma unroll 4
            for (int k = 0; k < 68; ++k)
                a += M2T[k][tid] * awx[k];
            xl[tid] = fmaxf(a, 0.f);
        }
        __syncthreads();

        // ---- phase F: gi = gWih @ o, k = 4*sg + 64*i ----
        {
            float a = 0.f;
#pragma unroll
            for (int i = 0; i < 8; ++i) {
                float4 w = wi8[i];
                float4 o4 = *(const float4*)&xl[4 * sg + 64 * i];
                a += w.x*o4.x + w.y*o4.y + w.z*o4.z + w.w*o4.w;
            }
            a += __shfl_xor(a, 1); a += __shfl_xor(a, 2);
            a += __shfl_xor(a, 4); a += __shfl_xor(a, 8);
            if (sg == 0 && rg < 24) gil[rg] = a;
        }
        __syncthreads();

        // ---- phase G: GRU combine + publish (8 threads) ----
        if (tid < 8) {
            float gh0 = biasg[tid] + ghl[tid];
            float gh1 = biasg[8 + tid] + ghl[8 + tid];
            float gh2 = biasg[16 + tid] + ghl[16 + tid];
            float gi0 = biasi[tid] + gil[tid];
            float gi1 = biasi[8 + tid] + gil[8 + tid];
            float gi2 = biasi[16 + tid] + gil[16 + tid];
            float r_ = sigf(gi0 + gh0);
            float z_ = sigf(gi1 + gh1);
            float n_ = tanh_f(gi2 + r_ * gh2);
            float hnew = (1.f - z_) * n_ + z_ * hL[dbase + tid];
            gstll(&hdec_p[(size_t)((s + 1) & 1) * 512 + dbase + tid], packfe(hnew, s + 1));
        }
        __syncthreads();   // protect hL/awx/xl before next-step overwrite
    }

    // epilogue: logits for s=29 (block 0 only)
    if (bid == 0) {
        {
            const ull* hs = hdec_p + (size_t)(30 & 1) * 512;
            ull v0 = gldll(hs + tid);
            while ((int)(v0 >> 32) != 30) {
                __builtin_amdgcn_s_sleep(1);
                v0 = gldll(hs + tid);
            }
            hL[tid] = lowf(v0);
        }
        __syncthreads();
        {
            float a = 0.f;
            float4 h0 = *(const float4*)&hL[4 * lane];
            float4 h1 = *(const float4*)&hL[4 * lane + 256];
            a += wo2[0].x*h0.x + wo2[0].y*h0.y + wo2[0].z*h0.z + wo2[0].w*h0.w;
            a += wo2[1].x*h1.x + wo2[1].y*h1.y + wo2[1].z*h1.z + wo2[1].w*h1.w;
#pragma unroll
            for (int off = 32; off; off >>= 1) a += __shfl_xor(a, off);
            if (lane == 0) zd[wv] = a;
        }
        __syncthreads();
        if (tid < 8) {
            float a = zd[tid] + outbL[tid];
            float m = a;
            m = fmaxf(m, __shfl_xor(m, 1));
            m = fmaxf(m, __shfl_xor(m, 2));
            m = fmaxf(m, __shfl_xor(m, 4));
            float e = __expf(a - m);
            float ss2 = e;
            ss2 += __shfl_xor(ss2, 1);
            ss2 += __shfl_xor(ss2, 2);
            ss2 += __shfl_xor(ss2, 4);
            dout[29 * 8 + tid] = a - m - __logf(ss2);
        }
    }
}

// ---------------------------------------------------------------------------
extern "C" void kernel_launch(void* const* d_in, const int* in_sizes, int n_in,
                              void* d_out, int out_size, void* d_ws, size_t ws_size,
                              hipStream_t stream) {
    (void)in_sizes; (void)n_in; (void)out_size; (void)ws_size;
    const float* data    = (const float*)d_in[0];
    const float* enc_Wih = (const float*)d_in[1];
    const float* enc_Whh = (const float*)d_in[2];
    const float* enc_bih = (const float*)d_in[3];
    const float* enc_bhh = (const float*)d_in[4];
    const float* p1f_Wih = (const float*)d_in[5];
    const float* p1f_Whh = (const float*)d_in[6];
    const float* p1f_bih = (const float*)d_in[7];
    const float* p1f_bhh = (const float*)d_in[8];
    const float* p1b_Wih = (const float*)d_in[9];
    const float* p1b_Whh = (const float*)d_in[10];
    const float* p1b_bih = (const float*)d_in[11];
    const float* p1b_bhh = (const float*)d_in[12];
    const float* p2f_Wih = (const float*)d_in[13];
    const float* p2f_Whh = (const float*)d_in[14];
    const float* p2f_bih = (const float*)d_in[15];
    const float* p2f_bhh = (const float*)d_in[16];
    const float* p2b_Wih = (const float*)d_in[17];
    const float* p2b_Whh = (const float*)d_in[18];
    const float* p2b_bih = (const float*)d_in[19];
    const float* p2b_bhh = (const float*)d_in[20];
    const float* attn_W  = (const float*)d_in[21];
    const float* attn_b  = (const float*)d_in[22];
    const float* comb_W  = (const float*)d_in[23];
    const float* comb_b  = (const float*)d_in[24];
    const float* gru_Wih = (const float*)d_in[25];
    const float* gru_Whh = (const float*)d_in[26];
    const float* gru_bih = (const float*)d_in[27];
    const float* gru_bhh = (const float*)d_in[28];
    const float* out_W   = (const float*)d_in[29];
    const float* out_b   = (const float*)d_in[30];

    float* ws = (float*)d_ws;
    // zeroed region [0 .. 256000)
    ull* hbufF   = (ull*)ws;                 // 245760 floats = [2][15][4096] ull
    ull* hp1     = (ull*)(ws + 245760);      // 4096 floats = [2][2][512] ull
    ull* hp2     = (ull*)(ws + 249856);      // 4096 floats
    ull* hdec_p  = (ull*)(ws + 253952);      // 2048 floats = [2][512] ull -> end 256000
    // non-zeroed scratch
    float* henc  = ws + 256000;              // 122880
    float* xp1f  = ws + 378880;              // 245760
    float* xp1b  = ws + 624640;              // 245760
    float* f1    = ws + 870400;              // 61440
    float* b1o   = ws + 931840;              // 61440
    float* x2    = ws + 993280;              // 122880
    float* xp2f  = ws + 1116160;             // 122880
    float* xp2b  = ws + 1239040;             // 122880
    float* f2    = ws + 1361920;             // 30720
    float* b2o   = ws + 1392640;             // 30720
    float* ctxb  = ws + 1423360;             // 61440
    float* MgT   = ws + 1484800;             // 30720 -> end 1515520

    init_k<<<256, 256, 0, stream>>>(ws);

    enc_all<<<240, 256, 0, stream>>>(data, enc_Wih, enc_Whh, enc_bih, enc_bhh,
                                     hbufF, henc);
    gemm_xp2<<<256, 256, 0, stream>>>(henc, 120, 1024, 128,
                                      p1f_Wih, p1f_bih, p1f_bhh, xp1f,
                                      p1b_Wih, p1b_bih, p1b_bhh, xp1b);
    pyr_rec<<<128, 256, 0, stream>>>(xp1f, xp1b, p1f_Whh, p1b_Whh, hp1, f1, b1o, 120);
    x2_assemble<<<60, 256, 0, stream>>>(f1, b1o, x2);
    gemm_xp2<<<128, 256, 0, stream>>>(x2, 60, 2048, 64,
                                      p2f_Wih, p2f_bih, p2f_bhh, xp2f,
                                      p2b_Wih, p2b_bih, p2b_bhh, xp2b);
    pyr_rec<<<128, 256, 0, stream>>>(xp2f, xp2b, p2f_Whh, p2b_Whh, hp2, f2, b2o, 60);
    ctx_k<<<60, 256, 0, stream>>>(f2, b2o, ctxb, hdec_p);
    precomp_M<<<64, 256, 0, stream>>>(comb_W, ctxb, MgT);
    dec_k<<<64, 512, 0, stream>>>(attn_W, attn_b, comb_W, comb_b,
                                  gru_Wih, gru_Whh, gru_bih, gru_bhh,
                                  out_W, out_b, MgT, hdec_p,
                                  (float*)d_out);
}